// Round 4
// baseline (231.529 us; speedup 1.0000x reference)
//
#include <hip/hip_runtime.h>
#include <hip/hip_bf16.h>
#include <cstdint>
#include <cstddef>

#define B_ 2
#define S_ 2048
#define D_ 768
#define H_ 12
#define M_ 64
#define BS_ (B_ * S_)
#define NQKV_ 2304            // 3 * 768 packed output columns

typedef __attribute__((ext_vector_type(8))) short bf16x8;
typedef __attribute__((ext_vector_type(4))) float f32x4;

__device__ __forceinline__ unsigned short f2bu(float f) {
    __hip_bfloat16 h = __float2bfloat16(f);   // RNE
    unsigned short u;
    __builtin_memcpy(&u, &h, 2);
    return u;
}
__device__ __forceinline__ unsigned pack2(float a, float b) {
    return (unsigned)f2bu(a) | ((unsigned)f2bu(b) << 16);
}

// Alias-safe vector load/store (memcpy => char semantics, still b128 ops).
__device__ __forceinline__ bf16x8 ld16(const unsigned short* p) {
    p = (const unsigned short*)__builtin_assume_aligned(p, 16);
    bf16x8 v; __builtin_memcpy(&v, p, 16); return v;
}
__device__ __forceinline__ uint4 ld16u(const unsigned short* p) {
    p = (const unsigned short*)__builtin_assume_aligned(p, 16);
    uint4 v; __builtin_memcpy(&v, p, 16); return v;
}
__device__ __forceinline__ void st16(unsigned short* p, uint4 v) {
    p = (unsigned short*)__builtin_assume_aligned(p, 16);
    __builtin_memcpy(p, &v, 16);
}
__device__ __forceinline__ float4 ldf4(const float* p) {
    p = (const float*)__builtin_assume_aligned(p, 16);
    float4 v; __builtin_memcpy(&v, p, 16); return v;
}

#define NEG_BIG (-3.0e38f)

// ---------------------------------------------------------------------------
// Pack W_Q/W_K/W_V [3][H,D,M] fp32 -> WT[2304][768] bf16 (B^T: row=out col).
// grid (9, 24): 256 cols per block-x, 32 k per block-y.
// ---------------------------------------------------------------------------
__global__ void pack_wqkv(const float* __restrict__ WQ,
                          const float* __restrict__ WK,
                          const float* __restrict__ WV,
                          unsigned short* __restrict__ WT)
{
    const int c  = blockIdx.x * 256 + threadIdx.x;   // 0..2303
    const int k0 = blockIdx.y * 32;
    const int which = c / D_;
    const int r = c - which * D_;
    const int h = r >> 6, m = r & 63;
    const float* Wsel = (which == 0) ? WQ : (which == 1) ? WK : WV;
    const float* src = Wsel + (size_t)h * D_ * M_ + m;
    unsigned short* dst = WT + (size_t)c * D_ + k0;
    for (int i = 0; i < 32; i += 8) {
        float wv[8];
#pragma unroll
        for (int j = 0; j < 8; j++) wv[j] = src[(size_t)(k0 + i + j) * M_];
        uint4 pu;
        pu.x = pack2(wv[0], wv[1]); pu.y = pack2(wv[2], wv[3]);
        pu.z = pack2(wv[4], wv[5]); pu.w = pack2(wv[6], wv[7]);
        st16(dst + i, pu);
    }
}

// ---------------------------------------------------------------------------
// Pack W_O [768][768] fp32 (k,d) -> WOT[768][768] bf16 (B^T: row=d, col=k).
// grid (3, 24).
// ---------------------------------------------------------------------------
__global__ void pack_wo(const float* __restrict__ WO, unsigned short* __restrict__ WOT)
{
    const int c  = blockIdx.x * 256 + threadIdx.x;   // output row d, 0..767
    const int k0 = blockIdx.y * 32;
    unsigned short* dst = WOT + (size_t)c * D_ + k0;
    for (int i = 0; i < 32; i += 8) {
        float wv[8];
#pragma unroll
        for (int j = 0; j < 8; j++) wv[j] = WO[(size_t)(k0 + i + j) * D_ + c];
        uint4 pu;
        pu.x = pack2(wv[0], wv[1]); pu.y = pack2(wv[2], wv[3]);
        pu.z = pack2(wv[4], wv[5]); pu.w = pack2(wv[6], wv[7]);
        st16(dst + i, pu);
    }
}

// ---------------------------------------------------------------------------
// Kernel: fused QKV projection GEMM.  C[4096][2304] = x(fp32->bf16) @ WT^T.
// 128x128 tile, BK=32, 4 waves in 2x2 of 64x64.  Epilogue scatters to
// q/k/v [B,H,S,M] with bias (+0.125 scale for Q).  grid (32, 18).
// ---------------------------------------------------------------------------
__global__ __launch_bounds__(256) void qkv_gemm(
    const float* __restrict__ x,              // [4096][768] fp32
    const unsigned short* __restrict__ WT,    // [2304][768] bf16
    const float* __restrict__ bQ, const float* __restrict__ bK,
    const float* __restrict__ bV,
    unsigned short* __restrict__ qo, unsigned short* __restrict__ ko,
    unsigned short* __restrict__ vo)
{
    const int row0 = blockIdx.x * 128;
    const int col0 = blockIdx.y * 128;
    const int t = threadIdx.x;
    const int w = t >> 6, lane = t & 63, quad = lane >> 4, l16 = lane & 15;
    const int wrow0 = (w & 1) * 64, wcol0 = (w >> 1) * 64;

    __shared__ unsigned short Ald[128][40];   // pad 32->40: conflict-free b128
    __shared__ unsigned short Bld[128][40];

    f32x4 acc[4][4] = {};

    const int srow = t >> 1;          // 0..127
    const int skh  = (t & 1) * 16;    // 0 or 16

    const float*          ap = x  + (size_t)(row0 + srow) * D_ + skh;
    const unsigned short* bp = WT + (size_t)(col0 + srow) * D_ + skh;

    for (int k0 = 0; k0 < D_; k0 += 32) {
        float4 a0 = ldf4(ap + k0),     a1 = ldf4(ap + k0 + 4);
        float4 a2 = ldf4(ap + k0 + 8), a3 = ldf4(ap + k0 + 12);
        uint4 bv0 = ld16u(bp + k0), bv1 = ld16u(bp + k0 + 8);
        uint4 av0, av1;
        av0.x = pack2(a0.x, a0.y); av0.y = pack2(a0.z, a0.w);
        av0.z = pack2(a1.x, a1.y); av0.w = pack2(a1.z, a1.w);
        av1.x = pack2(a2.x, a2.y); av1.y = pack2(a2.z, a2.w);
        av1.z = pack2(a3.x, a3.y); av1.w = pack2(a3.z, a3.w);

        __syncthreads();
        st16(&Ald[srow][skh], av0); st16(&Ald[srow][skh + 8], av1);
        st16(&Bld[srow][skh], bv0); st16(&Bld[srow][skh + 8], bv1);
        __syncthreads();

        bf16x8 af[4], bfm[4];
#pragma unroll
        for (int rt = 0; rt < 4; rt++)
            af[rt] = ld16(&Ald[wrow0 + rt * 16 + l16][quad * 8]);
#pragma unroll
        for (int st = 0; st < 4; st++)
            bfm[st] = ld16(&Bld[wcol0 + st * 16 + l16][quad * 8]);
#pragma unroll
        for (int rt = 0; rt < 4; rt++)
#pragma unroll
            for (int st = 0; st < 4; st++)
                acc[rt][st] = __builtin_amdgcn_mfma_f32_16x16x32_bf16(
                    af[rt], bfm[st], acc[rt][st], 0, 0, 0);
    }

    const int which = col0 / D_;                 // tile never spans a matrix
    const int colin = col0 - which * D_;
    const float* bias = (which == 0) ? bQ : (which == 1) ? bK : bV;
    unsigned short* outp = (which == 0) ? qo : (which == 1) ? ko : vo;
    const float scale = (which == 0) ? 0.125f : 1.0f;

#pragma unroll
    for (int st = 0; st < 4; st++) {
        const int cl = colin + wcol0 + st * 16 + l16;   // 0..767 within matrix
        const int h = cl >> 6, m = cl & 63;
        const float bval = bias[cl];
#pragma unroll
        for (int rt = 0; rt < 4; rt++) {
#pragma unroll
            for (int rr = 0; rr < 4; rr++) {
                const int R = row0 + wrow0 + rt * 16 + quad * 4 + rr;
                const int bb = R >> 11, s = R & (S_ - 1);
                outp[(((size_t)bb * H_ + h) * S_ + s) * M_ + m] =
                    f2bu((acc[rt][st][rr] + bval) * scale);
            }
        }
    }
}

// ---------------------------------------------------------------------------
// Kernel: causal flash attention per (b,h), 64-query tile per block.
// qt reversed so heaviest blocks dispatch first (load balance).
// ---------------------------------------------------------------------------
__global__ __launch_bounds__(256, 2) void attn_kernel(
    const unsigned short* __restrict__ Q,   // [B,H,S,M] bf16 (scaled)
    const unsigned short* __restrict__ Kin, // [B,H,S,M] bf16
    const unsigned short* __restrict__ Vin, // [B,H,S,M] bf16
    unsigned short* __restrict__ Z)         // [B,S,H*M] bf16
{
    const int qt = (gridDim.x - 1) - blockIdx.x;   // heavy tiles first
    const int bh = blockIdx.y;
    const int b = bh / H_, h = bh - b * H_;

    const int t = threadIdx.x;
    const int wave = t >> 6, lane = t & 63, quad = lane >> 4, l16 = lane & 15;

    const unsigned short* Qb = Q   + ((size_t)bh * S_ + qt * 64) * M_;
    const unsigned short* Kb = Kin + (size_t)bh * S_ * M_;
    const unsigned short* Vb = Vin + (size_t)bh * S_ * M_;

    __shared__ unsigned short Klds[64][72];     // [key][feat]
    __shared__ unsigned short Vlds[64][72];     // [feat][key] (transposed)
    __shared__ unsigned short Plds[4][16][72];  // per-wave P strip [q][key]

    bf16x8 qf0, qf1;
    {
        const unsigned short* qrow = Qb + (size_t)(wave * 16 + l16) * M_;
        qf0 = ld16(qrow + quad * 8);
        qf1 = ld16(qrow + 32 + quad * 8);
    }

    f32x4 o_acc[4] = {};
    float mrow[4] = {NEG_BIG, NEG_BIG, NEG_BIG, NEG_BIG};
    float lrow[4] = {0.f, 0.f, 0.f, 0.f};

    for (int kt = 0; kt <= qt; kt++) {
        const unsigned short* kbase = Kb + (size_t)kt * 64 * M_;
        const unsigned short* vbase = Vb + (size_t)kt * 64 * M_;

        uint4 kv0 = ld16u(kbase + (size_t)(t >> 2) * M_ + (t & 3) * 16);
        uint4 kv1 = ld16u(kbase + (size_t)(t >> 2) * M_ + (t & 3) * 16 + 8);
        unsigned short vv[16];
#pragma unroll
        for (int i = 0; i < 16; i++)
            vv[i] = vbase[(size_t)((t >> 6) * 16 + i) * M_ + (t & 63)];

        __syncthreads();
        st16(&Klds[t >> 2][(t & 3) * 16], kv0);
        st16(&Klds[t >> 2][(t & 3) * 16 + 8], kv1);
        uint4 v0, v1;
        v0.x = (unsigned)vv[0]  | ((unsigned)vv[1]  << 16);
        v0.y = (unsigned)vv[2]  | ((unsigned)vv[3]  << 16);
        v0.z = (unsigned)vv[4]  | ((unsigned)vv[5]  << 16);
        v0.w = (unsigned)vv[6]  | ((unsigned)vv[7]  << 16);
        v1.x = (unsigned)vv[8]  | ((unsigned)vv[9]  << 16);
        v1.y = (unsigned)vv[10] | ((unsigned)vv[11] << 16);
        v1.z = (unsigned)vv[12] | ((unsigned)vv[13] << 16);
        v1.w = (unsigned)vv[14] | ((unsigned)vv[15] << 16);
        st16(&Vlds[t & 63][(t >> 6) * 16], v0);
        st16(&Vlds[t & 63][(t >> 6) * 16 + 8], v1);
        __syncthreads();

        f32x4 s_acc[4];
#pragma unroll
        for (int st = 0; st < 4; st++) {
            f32x4 z4 = {0.f, 0.f, 0.f, 0.f};
            bf16x8 kb0 = ld16(&Klds[st * 16 + l16][quad * 8]);
            bf16x8 kb1 = ld16(&Klds[st * 16 + l16][32 + quad * 8]);
            z4 = __builtin_amdgcn_mfma_f32_16x16x32_bf16(qf0, kb0, z4, 0, 0, 0);
            z4 = __builtin_amdgcn_mfma_f32_16x16x32_bf16(qf1, kb1, z4, 0, 0, 0);
            s_acc[st] = z4;
        }

        if (kt == qt) {
#pragma unroll
            for (int st = 0; st < 4; st++)
#pragma unroll
                for (int r = 0; r < 4; r++)
                    if (st * 16 + l16 > wave * 16 + quad * 4 + r)
                        s_acc[st][r] = -1e30f;
        }

        float rmax[4];
#pragma unroll
        for (int r = 0; r < 4; r++)
            rmax[r] = fmaxf(fmaxf(s_acc[0][r], s_acc[1][r]),
                            fmaxf(s_acc[2][r], s_acc[3][r]));
#pragma unroll
        for (int off = 1; off < 16; off <<= 1)
#pragma unroll
            for (int r = 0; r < 4; r++)
                rmax[r] = fmaxf(rmax[r], __shfl_xor(rmax[r], off, 64));

        float mnew[4], alpha[4];
#pragma unroll
        for (int r = 0; r < 4; r++) {
            mnew[r]  = fmaxf(mrow[r], rmax[r]);
            alpha[r] = __expf(mrow[r] - mnew[r]);
            mrow[r]  = mnew[r];
        }

        float psum[4] = {0.f, 0.f, 0.f, 0.f};
#pragma unroll
        for (int st = 0; st < 4; st++) {
#pragma unroll
            for (int r = 0; r < 4; r++) {
                float p = __expf(s_acc[st][r] - mnew[r]);
                psum[r] += p;
                Plds[wave][quad * 4 + r][st * 16 + l16] = f2bu(p);
            }
        }
#pragma unroll
        for (int off = 1; off < 16; off <<= 1)
#pragma unroll
            for (int r = 0; r < 4; r++)
                psum[r] += __shfl_xor(psum[r], off, 64);

#pragma unroll
        for (int r = 0; r < 4; r++) lrow[r] = lrow[r] * alpha[r] + psum[r];
#pragma unroll
        for (int st = 0; st < 4; st++)
#pragma unroll
            for (int r = 0; r < 4; r++) o_acc[st][r] *= alpha[r];

        __syncthreads();

        bf16x8 pf0 = ld16(&Plds[wave][l16][quad * 8]);
        bf16x8 pf1 = ld16(&Plds[wave][l16][32 + quad * 8]);
#pragma unroll
        for (int st = 0; st < 4; st++) {
            bf16x8 vb0 = ld16(&Vlds[st * 16 + l16][quad * 8]);
            bf16x8 vb1 = ld16(&Vlds[st * 16 + l16][32 + quad * 8]);
            o_acc[st] = __builtin_amdgcn_mfma_f32_16x16x32_bf16(pf0, vb0, o_acc[st], 0, 0, 0);
            o_acc[st] = __builtin_amdgcn_mfma_f32_16x16x32_bf16(pf1, vb1, o_acc[st], 0, 0, 0);
        }
    }

    float inv[4];
#pragma unroll
    for (int r = 0; r < 4; r++) inv[r] = 1.0f / lrow[r];
#pragma unroll
    for (int st = 0; st < 4; st++) {
#pragma unroll
        for (int r = 0; r < 4; r++) {
            const int q    = qt * 64 + wave * 16 + quad * 4 + r;
            const int feat = st * 16 + l16;
            Z[((size_t)b * S_ + q) * (H_ * M_) + h * M_ + feat] =
                f2bu(o_acc[st][r] * inv[r]);
        }
    }
}

// ---------------------------------------------------------------------------
// Kernel: output projection GEMM. out[4096][768] = Z(bf16) @ WOT^T + bO (fp32).
// Same 128x128 structure.  grid (32, 6).
// ---------------------------------------------------------------------------
__global__ __launch_bounds__(256) void oproj_gemm(
    const unsigned short* __restrict__ Zin,   // [4096][768] bf16
    const unsigned short* __restrict__ WOT,   // [768][768] bf16 (B^T)
    const float* __restrict__ bO,             // [768] fp32
    float* __restrict__ out)                  // [4096][768] fp32
{
    const int row0 = blockIdx.x * 128;
    const int col0 = blockIdx.y * 128;
    const int t = threadIdx.x;
    const int w = t >> 6, lane = t & 63, quad = lane >> 4, l16 = lane & 15;
    const int wrow0 = (w & 1) * 64, wcol0 = (w >> 1) * 64;

    __shared__ unsigned short Ald[128][40];
    __shared__ unsigned short Bld[128][40];

    f32x4 acc[4][4] = {};

    const int srow = t >> 1;
    const int skh  = (t & 1) * 16;

    const unsigned short* ap = Zin + (size_t)(row0 + srow) * D_ + skh;
    const unsigned short* bp = WOT + (size_t)(col0 + srow) * D_ + skh;

    for (int k0 = 0; k0 < D_; k0 += 32) {
        uint4 av0 = ld16u(ap + k0), av1 = ld16u(ap + k0 + 8);
        uint4 bv0 = ld16u(bp + k0), bv1 = ld16u(bp + k0 + 8);

        __syncthreads();
        st16(&Ald[srow][skh], av0); st16(&Ald[srow][skh + 8], av1);
        st16(&Bld[srow][skh], bv0); st16(&Bld[srow][skh + 8], bv1);
        __syncthreads();

        bf16x8 af[4], bfm[4];
#pragma unroll
        for (int rt = 0; rt < 4; rt++)
            af[rt] = ld16(&Ald[wrow0 + rt * 16 + l16][quad * 8]);
#pragma unroll
        for (int st = 0; st < 4; st++)
            bfm[st] = ld16(&Bld[wcol0 + st * 16 + l16][quad * 8]);
#pragma unroll
        for (int rt = 0; rt < 4; rt++)
#pragma unroll
            for (int st = 0; st < 4; st++)
                acc[rt][st] = __builtin_amdgcn_mfma_f32_16x16x32_bf16(
                    af[rt], bfm[st], acc[rt][st], 0, 0, 0);
    }

#pragma unroll
    for (int st = 0; st < 4; st++) {
        const int c = col0 + wcol0 + st * 16 + l16;
        const float bval = bO[c];
#pragma unroll
        for (int rt = 0; rt < 4; rt++) {
#pragma unroll
            for (int rr = 0; rr < 4; rr++) {
                const int R = row0 + wrow0 + rt * 16 + quad * 4 + rr;
                out[(size_t)R * D_ + c] = acc[rt][st][rr] + bval;
            }
        }
    }
}

// ---------------------------------------------------------------------------
extern "C" void kernel_launch(void* const* d_in, const int* in_sizes, int n_in,
                              void* d_out, int out_size, void* d_ws, size_t ws_size,
                              hipStream_t stream)
{
    const float* x  = (const float*)d_in[0];
    const float* WQ = (const float*)d_in[1];
    const float* bQ = (const float*)d_in[2];
    const float* WK = (const float*)d_in[3];
    const float* bK = (const float*)d_in[4];
    const float* WV = (const float*)d_in[5];
    const float* bV = (const float*)d_in[6];
    const float* WO = (const float*)d_in[7];
    const float* bO = (const float*)d_in[8];
    float* out = (float*)d_out;

    const size_t n = (size_t)B_ * H_ * S_ * M_;     // 3,145,728 elems
    unsigned short* q_ws  = (unsigned short*)d_ws;  // [B,H,S,M] bf16 (scaled)
    unsigned short* k_ws  = q_ws + n;
    unsigned short* v_ws  = k_ws + n;
    unsigned short* z_ws  = v_ws + n;               // [B,S,H*M] bf16
    unsigned short* WT    = z_ws + n;               // [2304][768] bf16
    unsigned short* WOT   = WT + (size_t)NQKV_ * D_;// [768][768] bf16

    pack_wqkv<<<dim3(9, 24), 256, 0, stream>>>(WQ, WK, WV, WT);
    pack_wo<<<dim3(3, 24), 256, 0, stream>>>(WO, WOT);
    qkv_gemm<<<dim3(BS_ / 128, NQKV_ / 128), 256, 0, stream>>>(
        x, WT, bQ, bK, bV, q_ws, k_ws, v_ws);
    attn_kernel<<<dim3(S_ / 64, B_ * H_), 256, 0, stream>>>(
        q_ws, k_ws, v_ws, z_ws);
    oproj_gemm<<<dim3(BS_ / 128, D_ / 128), 256, 0, stream>>>(
        z_ws, WOT, bO, out);
}

// Round 5
// 217.515 us; speedup vs baseline: 1.0644x; 1.0644x over previous
//
#include <hip/hip_runtime.h>
#include <hip/hip_bf16.h>
#include <cstdint>
#include <cstddef>

#define B_ 2
#define S_ 2048
#define D_ 768
#define H_ 12
#define M_ 64
#define BS_ (B_ * S_)
#define NQKV_ 2304            // 3 * 768 packed output columns

typedef __attribute__((ext_vector_type(8))) short bf16x8;
typedef __attribute__((ext_vector_type(4))) float f32x4;

__device__ __forceinline__ unsigned short f2bu(float f) {
    __hip_bfloat16 h = __float2bfloat16(f);   // RNE
    unsigned short u;
    __builtin_memcpy(&u, &h, 2);
    return u;
}
__device__ __forceinline__ unsigned pack2(float a, float b) {
    return (unsigned)f2bu(a) | ((unsigned)f2bu(b) << 16);
}

// Alias-safe vector load/store (memcpy => char semantics, still b128 ops).
__device__ __forceinline__ bf16x8 ld16(const unsigned short* p) {
    p = (const unsigned short*)__builtin_assume_aligned(p, 16);
    bf16x8 v; __builtin_memcpy(&v, p, 16); return v;
}
__device__ __forceinline__ uint4 ld16u(const unsigned short* p) {
    p = (const unsigned short*)__builtin_assume_aligned(p, 16);
    uint4 v; __builtin_memcpy(&v, p, 16); return v;
}
__device__ __forceinline__ void st16(unsigned short* p, uint4 v) {
    p = (unsigned short*)__builtin_assume_aligned(p, 16);
    __builtin_memcpy(p, &v, 16);
}
__device__ __forceinline__ float4 ldf4(const float* p) {
    p = (const float*)__builtin_assume_aligned(p, 16);
    float4 v; __builtin_memcpy(&v, p, 16); return v;
}

#define NEG_BIG (-3.0e38f)

// ---------------------------------------------------------------------------
// x fp32 -> bf16, row-major copy.  grid 1536 x 256, 8 elems/thread.
// ---------------------------------------------------------------------------
__global__ void xcvt(const float* __restrict__ x, unsigned short* __restrict__ xb)
{
    const size_t i = ((size_t)blockIdx.x * 256 + threadIdx.x) * 8;
    float4 a0 = ldf4(x + i), a1 = ldf4(x + i + 4);
    uint4 u;
    u.x = pack2(a0.x, a0.y); u.y = pack2(a0.z, a0.w);
    u.z = pack2(a1.x, a1.y); u.w = pack2(a1.z, a1.w);
    st16(xb + i, u);
}

// ---------------------------------------------------------------------------
// Pack W_Q/W_K/W_V [3][H,D,M] fp32 -> WT[2304][768] bf16 (B^T: row=out col).
// ---------------------------------------------------------------------------
__global__ void pack_wqkv(const float* __restrict__ WQ,
                          const float* __restrict__ WK,
                          const float* __restrict__ WV,
                          unsigned short* __restrict__ WT)
{
    const int c  = blockIdx.x * 256 + threadIdx.x;   // 0..2303
    const int k0 = blockIdx.y * 32;
    const int which = c / D_;
    const int r = c - which * D_;
    const int h = r >> 6, m = r & 63;
    const float* Wsel = (which == 0) ? WQ : (which == 1) ? WK : WV;
    const float* src = Wsel + (size_t)h * D_ * M_ + m;
    unsigned short* dst = WT + (size_t)c * D_ + k0;
    for (int i = 0; i < 32; i += 8) {
        float wv[8];
#pragma unroll
        for (int j = 0; j < 8; j++) wv[j] = src[(size_t)(k0 + i + j) * M_];
        uint4 pu;
        pu.x = pack2(wv[0], wv[1]); pu.y = pack2(wv[2], wv[3]);
        pu.z = pack2(wv[4], wv[5]); pu.w = pack2(wv[6], wv[7]);
        st16(dst + i, pu);
    }
}

// ---------------------------------------------------------------------------
// Pack W_O [768][768] fp32 (k,d) -> WOT[768][768] bf16 (B^T: row=d, col=k).
// ---------------------------------------------------------------------------
__global__ void pack_wo(const float* __restrict__ WO, unsigned short* __restrict__ WOT)
{
    const int c  = blockIdx.x * 256 + threadIdx.x;   // output row d, 0..767
    const int k0 = blockIdx.y * 32;
    unsigned short* dst = WOT + (size_t)c * D_ + k0;
    for (int i = 0; i < 32; i += 8) {
        float wv[8];
#pragma unroll
        for (int j = 0; j < 8; j++) wv[j] = WO[(size_t)(k0 + i + j) * D_ + c];
        uint4 pu;
        pu.x = pack2(wv[0], wv[1]); pu.y = pack2(wv[2], wv[3]);
        pu.z = pack2(wv[4], wv[5]); pu.w = pack2(wv[6], wv[7]);
        st16(dst + i, pu);
    }
}

// ---------------------------------------------------------------------------
// QKV projection GEMM. C[4096][2304] = xb @ WT^T.  128x128 tile, BK=64.
// Epilogue scatters to q/k/v [B,H,S,M] with bias (+0.125 for Q). grid (32,18).
// ---------------------------------------------------------------------------
__global__ __launch_bounds__(256, 2) void qkv_gemm(
    const unsigned short* __restrict__ xb,    // [4096][768] bf16
    const unsigned short* __restrict__ WT,    // [2304][768] bf16
    const float* __restrict__ bQ, const float* __restrict__ bK,
    const float* __restrict__ bV,
    unsigned short* __restrict__ qo, unsigned short* __restrict__ ko,
    unsigned short* __restrict__ vo)
{
    const int row0 = blockIdx.x * 128;
    const int col0 = blockIdx.y * 128;
    const int t = threadIdx.x;
    const int w = t >> 6, lane = t & 63, quad = lane >> 4, l16 = lane & 15;
    const int wrow0 = (w & 1) * 64, wcol0 = (w >> 1) * 64;

    __shared__ unsigned short Ald[128][72];
    __shared__ unsigned short Bld[128][72];

    f32x4 acc[4][4] = {};

    const int srow = t >> 1;          // 0..127
    const int skh  = (t & 1) * 32;    // 0 or 32

    const unsigned short* ap = xb + (size_t)(row0 + srow) * D_ + skh;
    const unsigned short* bp = WT + (size_t)(col0 + srow) * D_ + skh;

    for (int k0 = 0; k0 < D_; k0 += 64) {
        uint4 a[4], bb[4];
#pragma unroll
        for (int j = 0; j < 4; j++) {
            a[j]  = ld16u(ap + k0 + 8 * j);
            bb[j] = ld16u(bp + k0 + 8 * j);
        }
        __syncthreads();
#pragma unroll
        for (int j = 0; j < 4; j++) {
            st16(&Ald[srow][skh + 8 * j], a[j]);
            st16(&Bld[srow][skh + 8 * j], bb[j]);
        }
        __syncthreads();

        bf16x8 af[4][2], bfm[4][2];
#pragma unroll
        for (int rt = 0; rt < 4; rt++)
#pragma unroll
            for (int c = 0; c < 2; c++)
                af[rt][c] = ld16(&Ald[wrow0 + rt * 16 + l16][c * 32 + quad * 8]);
#pragma unroll
        for (int st = 0; st < 4; st++)
#pragma unroll
            for (int c = 0; c < 2; c++)
                bfm[st][c] = ld16(&Bld[wcol0 + st * 16 + l16][c * 32 + quad * 8]);
#pragma unroll
        for (int rt = 0; rt < 4; rt++)
#pragma unroll
            for (int st = 0; st < 4; st++) {
                acc[rt][st] = __builtin_amdgcn_mfma_f32_16x16x32_bf16(
                    af[rt][0], bfm[st][0], acc[rt][st], 0, 0, 0);
                acc[rt][st] = __builtin_amdgcn_mfma_f32_16x16x32_bf16(
                    af[rt][1], bfm[st][1], acc[rt][st], 0, 0, 0);
            }
    }

    const int which = col0 / D_;                 // tile never spans a matrix
    const int colin = col0 - which * D_;
    const float* bias = (which == 0) ? bQ : (which == 1) ? bK : bV;
    unsigned short* outp = (which == 0) ? qo : (which == 1) ? ko : vo;
    const float scale = (which == 0) ? 0.125f : 1.0f;

#pragma unroll
    for (int st = 0; st < 4; st++) {
        const int cl = colin + wcol0 + st * 16 + l16;   // 0..767 within matrix
        const int h = cl >> 6, m = cl & 63;
        const float bval = bias[cl];
#pragma unroll
        for (int rt = 0; rt < 4; rt++) {
#pragma unroll
            for (int rr = 0; rr < 4; rr++) {
                const int R = row0 + wrow0 + rt * 16 + quad * 4 + rr;
                const int bb2 = R >> 11, s = R & (S_ - 1);
                outp[(((size_t)bb2 * H_ + h) * S_ + s) * M_ + m] =
                    f2bu((acc[rt][st][rr] + bval) * scale);
            }
        }
    }
}

// ---------------------------------------------------------------------------
// Causal flash attention: 64-query tile x 128-key tiles.  grid (32, 24).
// Per iter: stage K[128][64] + V^T[64][128], QK (8 st), online softmax,
// P->LDS->A-layout, PV.  3 blocks/CU at 52.7 KB LDS.
// ---------------------------------------------------------------------------
__global__ __launch_bounds__(256, 3) void attn_kernel(
    const unsigned short* __restrict__ Q,   // [B,H,S,M] bf16 (scaled)
    const unsigned short* __restrict__ Kin, // [B,H,S,M] bf16
    const unsigned short* __restrict__ Vin, // [B,H,S,M] bf16
    unsigned short* __restrict__ Z)         // [B,S,H*M] bf16
{
    const int qt = (int)(gridDim.x - 1) - (int)blockIdx.x;   // heavy first
    const int bh = blockIdx.y;
    const int b = bh / H_, h = bh - b * H_;

    const int t = threadIdx.x;
    const int wave = t >> 6, lane = t & 63, quad = lane >> 4, l16 = lane & 15;

    const unsigned short* Qb = Q   + ((size_t)bh * S_ + qt * 64) * M_;
    const unsigned short* Kb = Kin + (size_t)bh * S_ * M_;
    const unsigned short* Vb = Vin + (size_t)bh * S_ * M_;

    __shared__ unsigned short Klds[128][72];    // [key][feat]
    __shared__ unsigned short Vlds[64][136];    // [feat][key] transposed
    __shared__ unsigned short Plds[4][16][132]; // per-wave [qrow][key]

    bf16x8 qf[2];
    {
        const unsigned short* qrow = Qb + (size_t)(wave * 16 + l16) * M_;
        qf[0] = ld16(qrow + quad * 8);
        qf[1] = ld16(qrow + 32 + quad * 8);
    }

    f32x4 o_acc[4] = {};
    float mrow[4] = {NEG_BIG, NEG_BIG, NEG_BIG, NEG_BIG};
    float lrow[4] = {0.f, 0.f, 0.f, 0.f};

    const int lastkt = qt >> 1;
    for (int kt = 0; kt <= lastkt; kt++) {
        const unsigned short* kbase = Kb + (size_t)kt * 128 * M_;
        const unsigned short* vbase = Vb + (size_t)kt * 128 * M_;

        // K: thread t loads row t>>1, 32 feats at (t&1)*32
        uint4 ka[4];
#pragma unroll
        for (int j = 0; j < 4; j++)
            ka[j] = ld16u(kbase + (size_t)(t >> 1) * M_ + (t & 1) * 32 + 8 * j);
        // V gather (transpose): feat = t&63, keys wave*32..+31
        unsigned short vv[32];
#pragma unroll
        for (int i = 0; i < 32; i++)
            vv[i] = vbase[(size_t)((t >> 6) * 32 + i) * M_ + (t & 63)];

        __syncthreads();
#pragma unroll
        for (int j = 0; j < 4; j++)
            st16(&Klds[t >> 1][(t & 1) * 32 + 8 * j], ka[j]);
#pragma unroll
        for (int j = 0; j < 4; j++) {
            uint4 u;
            u.x = (unsigned)vv[8*j]   | ((unsigned)vv[8*j+1] << 16);
            u.y = (unsigned)vv[8*j+2] | ((unsigned)vv[8*j+3] << 16);
            u.z = (unsigned)vv[8*j+4] | ((unsigned)vv[8*j+5] << 16);
            u.w = (unsigned)vv[8*j+6] | ((unsigned)vv[8*j+7] << 16);
            st16(&Vlds[t & 63][(t >> 6) * 32 + 8 * j], u);
        }
        __syncthreads();

        // S = Q K^T over 128 keys (8 column strips)
        f32x4 s_acc[8];
#pragma unroll
        for (int st = 0; st < 8; st++) {
            f32x4 z4 = {0.f, 0.f, 0.f, 0.f};
            bf16x8 kb0 = ld16(&Klds[st * 16 + l16][quad * 8]);
            bf16x8 kb1 = ld16(&Klds[st * 16 + l16][32 + quad * 8]);
            z4 = __builtin_amdgcn_mfma_f32_16x16x32_bf16(qf[0], kb0, z4, 0, 0, 0);
            z4 = __builtin_amdgcn_mfma_f32_16x16x32_bf16(qf[1], kb1, z4, 0, 0, 0);
            s_acc[st] = z4;
        }

        // causal mask on last tile (keys may exceed queries)
        if (kt == lastkt) {
#pragma unroll
            for (int st = 0; st < 8; st++)
#pragma unroll
                for (int r = 0; r < 4; r++)
                    if (kt * 128 + st * 16 + l16 >
                        qt * 64 + wave * 16 + quad * 4 + r)
                        s_acc[st][r] = -1e30f;
        }

        float rmax[4];
#pragma unroll
        for (int r = 0; r < 4; r++) {
            float m0 = fmaxf(fmaxf(s_acc[0][r], s_acc[1][r]),
                             fmaxf(s_acc[2][r], s_acc[3][r]));
            float m1 = fmaxf(fmaxf(s_acc[4][r], s_acc[5][r]),
                             fmaxf(s_acc[6][r], s_acc[7][r]));
            rmax[r] = fmaxf(m0, m1);
        }
#pragma unroll
        for (int off = 1; off < 16; off <<= 1)
#pragma unroll
            for (int r = 0; r < 4; r++)
                rmax[r] = fmaxf(rmax[r], __shfl_xor(rmax[r], off, 64));

        float mnew[4], alpha[4];
#pragma unroll
        for (int r = 0; r < 4; r++) {
            mnew[r]  = fmaxf(mrow[r], rmax[r]);
            alpha[r] = __expf(mrow[r] - mnew[r]);
            mrow[r]  = mnew[r];
        }

        float psum[4] = {0.f, 0.f, 0.f, 0.f};
#pragma unroll
        for (int st = 0; st < 8; st++) {
#pragma unroll
            for (int r = 0; r < 4; r++) {
                float p = __expf(s_acc[st][r] - mnew[r]);
                psum[r] += p;
                Plds[wave][quad * 4 + r][st * 16 + l16] = f2bu(p);
            }
        }
#pragma unroll
        for (int off = 1; off < 16; off <<= 1)
#pragma unroll
            for (int r = 0; r < 4; r++)
                psum[r] += __shfl_xor(psum[r], off, 64);

#pragma unroll
        for (int r = 0; r < 4; r++) lrow[r] = lrow[r] * alpha[r] + psum[r];
#pragma unroll
        for (int st = 0; st < 4; st++)
#pragma unroll
            for (int r = 0; r < 4; r++) o_acc[st][r] *= alpha[r];

        __syncthreads();   // order the P round-trip (block converged anyway)

        // O += P V : P A-frags over 4 key-chunks, V^T B-frags over 4 feats
        bf16x8 pf[4];
#pragma unroll
        for (int c = 0; c < 4; c++)
            pf[c] = ld16(&Plds[wave][l16][c * 32 + quad * 8]);
#pragma unroll
        for (int st = 0; st < 4; st++) {
#pragma unroll
            for (int c = 0; c < 4; c++) {
                bf16x8 vb = ld16(&Vlds[st * 16 + l16][c * 32 + quad * 8]);
                o_acc[st] = __builtin_amdgcn_mfma_f32_16x16x32_bf16(
                    pf[c], vb, o_acc[st], 0, 0, 0);
            }
        }
    }

    float inv[4];
#pragma unroll
    for (int r = 0; r < 4; r++) inv[r] = 1.0f / lrow[r];
#pragma unroll
    for (int st = 0; st < 4; st++) {
#pragma unroll
        for (int r = 0; r < 4; r++) {
            const int q    = qt * 64 + wave * 16 + quad * 4 + r;
            const int feat = st * 16 + l16;
            Z[((size_t)b * S_ + q) * (H_ * M_) + h * M_ + feat] =
                f2bu(o_acc[st][r] * inv[r]);
        }
    }
}

// ---------------------------------------------------------------------------
// Output projection GEMM. out[4096][768] = Z @ WOT^T + bO (fp32). BK=64.
// ---------------------------------------------------------------------------
__global__ __launch_bounds__(256, 2) void oproj_gemm(
    const unsigned short* __restrict__ Zin,   // [4096][768] bf16
    const unsigned short* __restrict__ WOT,   // [768][768] bf16 (B^T)
    const float* __restrict__ bO,             // [768] fp32
    float* __restrict__ out)                  // [4096][768] fp32
{
    const int row0 = blockIdx.x * 128;
    const int col0 = blockIdx.y * 128;
    const int t = threadIdx.x;
    const int w = t >> 6, lane = t & 63, quad = lane >> 4, l16 = lane & 15;
    const int wrow0 = (w & 1) * 64, wcol0 = (w >> 1) * 64;

    __shared__ unsigned short Ald[128][72];
    __shared__ unsigned short Bld[128][72];

    f32x4 acc[4][4] = {};

    const int srow = t >> 1;
    const int skh  = (t & 1) * 32;

    const unsigned short* ap = Zin + (size_t)(row0 + srow) * D_ + skh;
    const unsigned short* bp = WOT + (size_t)(col0 + srow) * D_ + skh;

    for (int k0 = 0; k0 < D_; k0 += 64) {
        uint4 a[4], bb[4];
#pragma unroll
        for (int j = 0; j < 4; j++) {
            a[j]  = ld16u(ap + k0 + 8 * j);
            bb[j] = ld16u(bp + k0 + 8 * j);
        }
        __syncthreads();
#pragma unroll
        for (int j = 0; j < 4; j++) {
            st16(&Ald[srow][skh + 8 * j], a[j]);
            st16(&Bld[srow][skh + 8 * j], bb[j]);
        }
        __syncthreads();

        bf16x8 af[4][2], bfm[4][2];
#pragma unroll
        for (int rt = 0; rt < 4; rt++)
#pragma unroll
            for (int c = 0; c < 2; c++)
                af[rt][c] = ld16(&Ald[wrow0 + rt * 16 + l16][c * 32 + quad * 8]);
#pragma unroll
        for (int st = 0; st < 4; st++)
#pragma unroll
            for (int c = 0; c < 2; c++)
                bfm[st][c] = ld16(&Bld[wcol0 + st * 16 + l16][c * 32 + quad * 8]);
#pragma unroll
        for (int rt = 0; rt < 4; rt++)
#pragma unroll
            for (int st = 0; st < 4; st++) {
                acc[rt][st] = __builtin_amdgcn_mfma_f32_16x16x32_bf16(
                    af[rt][0], bfm[st][0], acc[rt][st], 0, 0, 0);
                acc[rt][st] = __builtin_amdgcn_mfma_f32_16x16x32_bf16(
                    af[rt][1], bfm[st][1], acc[rt][st], 0, 0, 0);
            }
    }

#pragma unroll
    for (int st = 0; st < 4; st++) {
        const int c = col0 + wcol0 + st * 16 + l16;
        const float bval = bO[c];
#pragma unroll
        for (int rt = 0; rt < 4; rt++) {
#pragma unroll
            for (int rr = 0; rr < 4; rr++) {
                const int R = row0 + wrow0 + rt * 16 + quad * 4 + rr;
                out[(size_t)R * D_ + c] = acc[rt][st][rr] + bval;
            }
        }
    }
}

// ---------------------------------------------------------------------------
extern "C" void kernel_launch(void* const* d_in, const int* in_sizes, int n_in,
                              void* d_out, int out_size, void* d_ws, size_t ws_size,
                              hipStream_t stream)
{
    const float* x  = (const float*)d_in[0];
    const float* WQ = (const float*)d_in[1];
    const float* bQ = (const float*)d_in[2];
    const float* WK = (const float*)d_in[3];
    const float* bK = (const float*)d_in[4];
    const float* WV = (const float*)d_in[5];
    const float* bV = (const float*)d_in[6];
    const float* WO = (const float*)d_in[7];
    const float* bO = (const float*)d_in[8];
    float* out = (float*)d_out;

    const size_t n = (size_t)B_ * H_ * S_ * M_;     // 3,145,728 elems
    unsigned short* q_ws  = (unsigned short*)d_ws;  // [B,H,S,M] bf16 (scaled)
    unsigned short* k_ws  = q_ws + n;
    unsigned short* v_ws  = k_ws + n;
    unsigned short* z_ws  = v_ws + n;               // [B,S,H*M] bf16
    unsigned short* WT    = z_ws + n;               // [2304][768] bf16
    unsigned short* WOT   = WT + (size_t)NQKV_ * D_;// [768][768] bf16
    unsigned short* xb    = WOT + (size_t)D_ * D_;  // [4096][768] bf16

    xcvt<<<dim3((BS_ * D_) / (256 * 8)), 256, 0, stream>>>(x, xb);
    pack_wqkv<<<dim3(9, 24), 256, 0, stream>>>(WQ, WK, WV, WT);
    pack_wo<<<dim3(3, 24), 256, 0, stream>>>(WO, WOT);
    qkv_gemm<<<dim3(BS_ / 128, NQKV_ / 128), 256, 0, stream>>>(
        xb, WT, bQ, bK, bV, q_ws, k_ws, v_ws);
    attn_kernel<<<dim3(S_ / 64, B_ * H_), 256, 0, stream>>>(
        q_ws, k_ws, v_ws, z_ws);
    oproj_gemm<<<dim3(BS_ / 128, D_ / 128), 256, 0, stream>>>(
        z_ws, WOT, bO, out);
}

// Round 6
// 213.652 us; speedup vs baseline: 1.0837x; 1.0181x over previous
//
#include <hip/hip_runtime.h>
#include <hip/hip_bf16.h>
#include <cstdint>
#include <cstddef>

#define B_ 2
#define S_ 2048
#define D_ 768
#define H_ 12
#define M_ 64
#define BS_ (B_ * S_)
#define NQKV_ 2304            // 3 * 768 packed output columns
#define NCHUNK_ 80            // compact chunks per bh (sum of ceil((qt+1)/8))
#define TOTCHUNK_ (24 * NCHUNK_)   // 1920

typedef __attribute__((ext_vector_type(8))) short bf16x8;
typedef __attribute__((ext_vector_type(4))) float f32x4;

__device__ __forceinline__ unsigned short f2bu(float f) {
    __hip_bfloat16 h = __float2bfloat16(f);   // RNE
    unsigned short u;
    __builtin_memcpy(&u, &h, 2);
    return u;
}
__device__ __forceinline__ unsigned pack2(float a, float b) {
    return (unsigned)f2bu(a) | ((unsigned)f2bu(b) << 16);
}

// Alias-safe vector load/store (memcpy => char semantics, still b128 ops).
__device__ __forceinline__ bf16x8 ld16(const unsigned short* p) {
    p = (const unsigned short*)__builtin_assume_aligned(p, 16);
    bf16x8 v; __builtin_memcpy(&v, p, 16); return v;
}
__device__ __forceinline__ uint4 ld16u(const unsigned short* p) {
    p = (const unsigned short*)__builtin_assume_aligned(p, 16);
    uint4 v; __builtin_memcpy(&v, p, 16); return v;
}
__device__ __forceinline__ void st16(unsigned short* p, uint4 v) {
    p = (unsigned short*)__builtin_assume_aligned(p, 16);
    __builtin_memcpy(p, &v, 16);
}
__device__ __forceinline__ float4 ldf4(const float* p) {
    p = (const float*)__builtin_assume_aligned(p, 16);
    float4 v; __builtin_memcpy(&v, p, 16); return v;
}
__device__ __forceinline__ void stf4(float* p, float4 v) {
    p = (float*)__builtin_assume_aligned(p, 16);
    __builtin_memcpy(p, &v, 16);
}

#define NEG_BIG (-3.0e38f)

// ---------------------------------------------------------------------------
// prep: fused weight packing.
//  blocks [0,216): W_Q/K/V [3][H,D,M] fp32 -> WT[2304][768] bf16 (B^T)
//  blocks [216,288): W_O [768][768] fp32 (k,d) -> WOT[768][768] bf16 (B^T)
// ---------------------------------------------------------------------------
__global__ void prep(const float* __restrict__ WQ, const float* __restrict__ WK,
                     const float* __restrict__ WV, const float* __restrict__ WO,
                     unsigned short* __restrict__ WT,
                     unsigned short* __restrict__ WOT)
{
    const int bx = blockIdx.x;
    if (bx < 216) {
        const int xx = bx % 9, yy = bx / 9;
        const int c  = xx * 256 + threadIdx.x;   // 0..2303
        const int k0 = yy * 32;
        const int which = c / D_;
        const int r = c - which * D_;
        const int h = r >> 6, m = r & 63;
        const float* Wsel = (which == 0) ? WQ : (which == 1) ? WK : WV;
        const float* src = Wsel + (size_t)h * D_ * M_ + m;
        unsigned short* dst = WT + (size_t)c * D_ + k0;
        for (int i = 0; i < 32; i += 8) {
            float wv[8];
#pragma unroll
            for (int j = 0; j < 8; j++) wv[j] = src[(size_t)(k0 + i + j) * M_];
            uint4 pu;
            pu.x = pack2(wv[0], wv[1]); pu.y = pack2(wv[2], wv[3]);
            pu.z = pack2(wv[4], wv[5]); pu.w = pack2(wv[6], wv[7]);
            st16(dst + i, pu);
        }
    } else {
        const int b2 = bx - 216;
        const int xx = b2 % 3, yy = b2 / 3;
        const int c  = xx * 256 + threadIdx.x;   // output row d, 0..767
        const int k0 = yy * 32;
        unsigned short* dst = WOT + (size_t)c * D_ + k0;
        for (int i = 0; i < 32; i += 8) {
            float wv[8];
#pragma unroll
            for (int j = 0; j < 8; j++) wv[j] = WO[(size_t)(k0 + i + j) * D_ + c];
            uint4 pu;
            pu.x = pack2(wv[0], wv[1]); pu.y = pack2(wv[2], wv[3]);
            pu.z = pack2(wv[4], wv[5]); pu.w = pack2(wv[6], wv[7]);
            st16(dst + i, pu);
        }
    }
}

// ---------------------------------------------------------------------------
// QKV projection GEMM. C[4096][2304] = x(fp32->bf16 inline) @ WT^T.
// 128x128 tile, BK=64.  Epilogue scatters to q/k/v [B,H,S,M] with bias
// (+0.125 scale for Q). grid (32,18).
// ---------------------------------------------------------------------------
__global__ __launch_bounds__(256, 2) void qkv_gemm(
    const float* __restrict__ x,              // [4096][768] fp32
    const unsigned short* __restrict__ WT,    // [2304][768] bf16
    const float* __restrict__ bQ, const float* __restrict__ bK,
    const float* __restrict__ bV,
    unsigned short* __restrict__ qo, unsigned short* __restrict__ ko,
    unsigned short* __restrict__ vo)
{
    const int row0 = blockIdx.x * 128;
    const int col0 = blockIdx.y * 128;
    const int t = threadIdx.x;
    const int w = t >> 6, lane = t & 63, quad = lane >> 4, l16 = lane & 15;
    const int wrow0 = (w & 1) * 64, wcol0 = (w >> 1) * 64;

    __shared__ unsigned short Ald[128][72];
    __shared__ unsigned short Bld[128][72];

    f32x4 acc[4][4] = {};

    const int srow = t >> 1;          // 0..127
    const int skh  = (t & 1) * 32;    // 0 or 32

    const float*          ap = x  + (size_t)(row0 + srow) * D_ + skh;
    const unsigned short* bp = WT + (size_t)(col0 + srow) * D_ + skh;

    for (int k0 = 0; k0 < D_; k0 += 64) {
        float4 f[8];
#pragma unroll
        for (int j = 0; j < 8; j++) f[j] = ldf4(ap + k0 + 4 * j);
        uint4 bb[4];
#pragma unroll
        for (int j = 0; j < 4; j++) bb[j] = ld16u(bp + k0 + 8 * j);
        uint4 a[4];
#pragma unroll
        for (int j = 0; j < 4; j++) {
            a[j].x = pack2(f[2*j].x, f[2*j].y);
            a[j].y = pack2(f[2*j].z, f[2*j].w);
            a[j].z = pack2(f[2*j+1].x, f[2*j+1].y);
            a[j].w = pack2(f[2*j+1].z, f[2*j+1].w);
        }

        __syncthreads();
#pragma unroll
        for (int j = 0; j < 4; j++) {
            st16(&Ald[srow][skh + 8 * j], a[j]);
            st16(&Bld[srow][skh + 8 * j], bb[j]);
        }
        __syncthreads();

        bf16x8 af[4][2], bfm[4][2];
#pragma unroll
        for (int rt = 0; rt < 4; rt++)
#pragma unroll
            for (int c = 0; c < 2; c++)
                af[rt][c] = ld16(&Ald[wrow0 + rt * 16 + l16][c * 32 + quad * 8]);
#pragma unroll
        for (int st = 0; st < 4; st++)
#pragma unroll
            for (int c = 0; c < 2; c++)
                bfm[st][c] = ld16(&Bld[wcol0 + st * 16 + l16][c * 32 + quad * 8]);
#pragma unroll
        for (int rt = 0; rt < 4; rt++)
#pragma unroll
            for (int st = 0; st < 4; st++) {
                acc[rt][st] = __builtin_amdgcn_mfma_f32_16x16x32_bf16(
                    af[rt][0], bfm[st][0], acc[rt][st], 0, 0, 0);
                acc[rt][st] = __builtin_amdgcn_mfma_f32_16x16x32_bf16(
                    af[rt][1], bfm[st][1], acc[rt][st], 0, 0, 0);
            }
    }

    const int which = col0 / D_;                 // tile never spans a matrix
    const int colin = col0 - which * D_;
    const float* bias = (which == 0) ? bQ : (which == 1) ? bK : bV;
    unsigned short* outp = (which == 0) ? qo : (which == 1) ? ko : vo;
    const float scale = (which == 0) ? 0.125f : 1.0f;

#pragma unroll
    for (int st = 0; st < 4; st++) {
        const int cl = colin + wcol0 + st * 16 + l16;   // 0..767 within matrix
        const int h = cl >> 6, m = cl & 63;
        const float bval = bias[cl];
#pragma unroll
        for (int rt = 0; rt < 4; rt++) {
#pragma unroll
            for (int rr = 0; rr < 4; rr++) {
                const int R = row0 + wrow0 + rt * 16 + quad * 4 + rr;
                const int bb2 = R >> 11, s = R & (S_ - 1);
                outp[(((size_t)bb2 * H_ + h) * S_ + s) * M_ + m] =
                    f2bu((acc[rt][st][rr] + bval) * scale);
            }
        }
    }
}

// ---------------------------------------------------------------------------
// Split-K causal flash attention.  grid (80, 24): x = compact (qt, chunk)
// index, y = bh.  Each block: 64 queries x up to 512 keys (<=4 iters of 128),
// writes UNNORMALIZED partial O (fp32) + per-row (m, l) to workspace.
// Register prefetch of next K/V tile overlaps global latency with compute.
// ---------------------------------------------------------------------------
struct StageRegs { uint4 ka[4]; unsigned short vv[32]; };

__device__ __forceinline__ void load_tile(const unsigned short* kb,
                                          const unsigned short* vb,
                                          int t, StageRegs& s)
{
#pragma unroll
    for (int j = 0; j < 4; j++)
        s.ka[j] = ld16u(kb + (size_t)(t >> 1) * M_ + (t & 1) * 32 + 8 * j);
#pragma unroll
    for (int i = 0; i < 32; i++)
        s.vv[i] = vb[(size_t)((t >> 6) * 32 + i) * M_ + (t & 63)];
}

__global__ __launch_bounds__(256, 3) void attn_split(
    const unsigned short* __restrict__ Q,   // [B,H,S,M] bf16 (scaled)
    const unsigned short* __restrict__ Kin, // [B,H,S,M] bf16
    const unsigned short* __restrict__ Vin, // [B,H,S,M] bf16
    float* __restrict__ Opart,              // [1920][64][64] fp32
    float* __restrict__ ml)                 // [1920][128] fp32 (m then l)
{
    const int xx = blockIdx.x;              // 0..79 compact (qt, c)
    const int bh = blockIdx.y;

    int qt, c, nc;
    if (xx < 8)       { qt = xx; c = 0; nc = 1; }
    else if (xx < 24) { int u = xx - 8;  qt = 8  + (u >> 1); c = u & 1;  nc = 2; }
    else if (xx < 48) { int u = xx - 24; qt = 16 + u / 3;    c = u % 3;  nc = 3; }
    else              { int u = xx - 48; qt = 24 + (u >> 2); c = u & 3;  nc = 4; }

    const int ci     = bh * NCHUNK_ + xx;
    const int kbeg   = c * 512;
    const int keyend = min((qt + 1) * 64, kbeg + 512);
    const int iters  = (keyend - kbeg + 127) >> 7;
    const bool lastchunk = (c == nc - 1);

    const int t = threadIdx.x;
    const int wave = t >> 6, lane = t & 63, quad = lane >> 4, l16 = lane & 15;

    const unsigned short* Qb = Q   + ((size_t)bh * S_ + qt * 64) * M_;
    const unsigned short* Kb = Kin + (size_t)bh * S_ * M_;
    const unsigned short* Vb = Vin + (size_t)bh * S_ * M_;

    __shared__ unsigned short Klds[128][72];    // [key][feat]
    __shared__ unsigned short Vlds[64][136];    // [feat][key] transposed
    __shared__ unsigned short Plds[4][16][132]; // per-wave [qrow][key]

    bf16x8 qf[2];
    {
        const unsigned short* qrow = Qb + (size_t)(wave * 16 + l16) * M_;
        qf[0] = ld16(qrow + quad * 8);
        qf[1] = ld16(qrow + 32 + quad * 8);
    }

    f32x4 o_acc[4] = {};
    float mrow[4] = {NEG_BIG, NEG_BIG, NEG_BIG, NEG_BIG};
    float lrow[4] = {0.f, 0.f, 0.f, 0.f};

    StageRegs sr;
    load_tile(Kb + (size_t)kbeg * M_, Vb + (size_t)kbeg * M_, t, sr);

    for (int it = 0; it < iters; it++) {
        __syncthreads();
#pragma unroll
        for (int j = 0; j < 4; j++)
            st16(&Klds[t >> 1][(t & 1) * 32 + 8 * j], sr.ka[j]);
#pragma unroll
        for (int j = 0; j < 4; j++) {
            uint4 u;
            u.x = (unsigned)sr.vv[8*j]   | ((unsigned)sr.vv[8*j+1] << 16);
            u.y = (unsigned)sr.vv[8*j+2] | ((unsigned)sr.vv[8*j+3] << 16);
            u.z = (unsigned)sr.vv[8*j+4] | ((unsigned)sr.vv[8*j+5] << 16);
            u.w = (unsigned)sr.vv[8*j+6] | ((unsigned)sr.vv[8*j+7] << 16);
            st16(&Vlds[t & 63][(t >> 6) * 32 + 8 * j], u);
        }
        __syncthreads();

        if (it + 1 < iters) {   // prefetch next tile into registers
            const size_t off = (size_t)(kbeg + (it + 1) * 128) * M_;
            load_tile(Kb + off, Vb + off, t, sr);
        }

        // S = Q K^T over 128 keys (8 column strips)
        f32x4 s_acc[8];
#pragma unroll
        for (int st = 0; st < 8; st++) {
            f32x4 z4 = {0.f, 0.f, 0.f, 0.f};
            bf16x8 kb0 = ld16(&Klds[st * 16 + l16][quad * 8]);
            bf16x8 kb1 = ld16(&Klds[st * 16 + l16][32 + quad * 8]);
            z4 = __builtin_amdgcn_mfma_f32_16x16x32_bf16(qf[0], kb0, z4, 0, 0, 0);
            z4 = __builtin_amdgcn_mfma_f32_16x16x32_bf16(qf[1], kb1, z4, 0, 0, 0);
            s_acc[st] = z4;
        }

        // causal + padding mask (only the last iteration of the last chunk
        // can contain the diagonal; padding keys also satisfy key > q)
        if (lastchunk && it == iters - 1) {
            const int key0 = kbeg + it * 128;
            const int qrow = qt * 64 + wave * 16 + quad * 4;
#pragma unroll
            for (int st = 0; st < 8; st++)
#pragma unroll
                for (int r = 0; r < 4; r++)
                    if (key0 + st * 16 + l16 > qrow + r)
                        s_acc[st][r] = -1e30f;
        }

        float rmax[4];
#pragma unroll
        for (int r = 0; r < 4; r++) {
            float m0 = fmaxf(fmaxf(s_acc[0][r], s_acc[1][r]),
                             fmaxf(s_acc[2][r], s_acc[3][r]));
            float m1 = fmaxf(fmaxf(s_acc[4][r], s_acc[5][r]),
                             fmaxf(s_acc[6][r], s_acc[7][r]));
            rmax[r] = fmaxf(m0, m1);
        }
#pragma unroll
        for (int off = 1; off < 16; off <<= 1)
#pragma unroll
            for (int r = 0; r < 4; r++)
                rmax[r] = fmaxf(rmax[r], __shfl_xor(rmax[r], off, 64));

        float mnew[4], alpha[4];
#pragma unroll
        for (int r = 0; r < 4; r++) {
            mnew[r]  = fmaxf(mrow[r], rmax[r]);
            alpha[r] = __expf(mrow[r] - mnew[r]);
            mrow[r]  = mnew[r];
        }

        float psum[4] = {0.f, 0.f, 0.f, 0.f};
#pragma unroll
        for (int st = 0; st < 8; st++) {
#pragma unroll
            for (int r = 0; r < 4; r++) {
                float p = __expf(s_acc[st][r] - mnew[r]);
                psum[r] += p;
                Plds[wave][quad * 4 + r][st * 16 + l16] = f2bu(p);
            }
        }
#pragma unroll
        for (int off = 1; off < 16; off <<= 1)
#pragma unroll
            for (int r = 0; r < 4; r++)
                psum[r] += __shfl_xor(psum[r], off, 64);

#pragma unroll
        for (int r = 0; r < 4; r++) lrow[r] = lrow[r] * alpha[r] + psum[r];
#pragma unroll
        for (int st = 0; st < 4; st++)
#pragma unroll
            for (int r = 0; r < 4; r++) o_acc[st][r] *= alpha[r];

        __syncthreads();   // order the P round-trip

        bf16x8 pf[4];
#pragma unroll
        for (int cc = 0; cc < 4; cc++)
            pf[cc] = ld16(&Plds[wave][l16][cc * 32 + quad * 8]);
#pragma unroll
        for (int st = 0; st < 4; st++) {
#pragma unroll
            for (int cc = 0; cc < 4; cc++) {
                bf16x8 vb = ld16(&Vlds[st * 16 + l16][cc * 32 + quad * 8]);
                o_acc[st] = __builtin_amdgcn_mfma_f32_16x16x32_bf16(
                    pf[cc], vb, o_acc[st], 0, 0, 0);
            }
        }
    }

    // write unnormalized partials
    float* Op = Opart + (size_t)ci * 4096;
#pragma unroll
    for (int st = 0; st < 4; st++) {
#pragma unroll
        for (int r = 0; r < 4; r++) {
            const int q = wave * 16 + quad * 4 + r;
            Op[q * 64 + st * 16 + l16] = o_acc[st][r];
        }
    }
    if (l16 == 0) {
#pragma unroll
        for (int r = 0; r < 4; r++) {
            const int q = wave * 16 + quad * 4 + r;
            ml[(size_t)ci * 128 + q]      = mrow[r];
            ml[(size_t)ci * 128 + 64 + q] = lrow[r];
        }
    }
}

// ---------------------------------------------------------------------------
// Combine: merge <=4 partials per (bh, qt) into Z [B,S,H*M] bf16.
// grid (32, 24): x=qt, y=bh.  Thread t: q=t>>2, feats (t&3)*16..+15.
// ---------------------------------------------------------------------------
__global__ void combine(const float* __restrict__ Opart,
                        const float* __restrict__ ml,
                        unsigned short* __restrict__ Z)
{
    const int qt = blockIdx.x, bh = blockIdx.y;
    const int b = bh / H_, h = bh - b * H_;
    const int g = qt >> 3, r7 = qt & 7;
    const int nc = g + 1;
    const int base = bh * NCHUNK_ + qt + 4 * g * (g - 1) + r7 * g;

    const int t = threadIdx.x;
    const int q = t >> 2, fs = (t & 3) * 16;

    float m_c[4], l_c[4];
    float M = NEG_BIG;
    for (int c = 0; c < nc; c++) {
        m_c[c] = ml[(size_t)(base + c) * 128 + q];
        l_c[c] = ml[(size_t)(base + c) * 128 + 64 + q];
        M = fmaxf(M, m_c[c]);
    }
    float L = 0.f;
    float w_c[4];
    for (int c = 0; c < nc; c++) {
        w_c[c] = __expf(m_c[c] - M);
        L += l_c[c] * w_c[c];
    }
    const float invL = 1.0f / L;

    float o[16] = {};
    for (int c = 0; c < nc; c++) {
        const float* op = Opart + (size_t)(base + c) * 4096 + q * 64 + fs;
        const float wc = w_c[c];
#pragma unroll
        for (int j4 = 0; j4 < 4; j4++) {
            float4 v = ldf4(op + j4 * 4);
            o[j4*4+0] += wc * v.x; o[j4*4+1] += wc * v.y;
            o[j4*4+2] += wc * v.z; o[j4*4+3] += wc * v.w;
        }
    }

    unsigned short* zp = Z + ((size_t)b * S_ + qt * 64 + q) * (H_ * M_) + h * M_ + fs;
    uint4 u0, u1;
    u0.x = pack2(o[0]*invL,  o[1]*invL);  u0.y = pack2(o[2]*invL,  o[3]*invL);
    u0.z = pack2(o[4]*invL,  o[5]*invL);  u0.w = pack2(o[6]*invL,  o[7]*invL);
    u1.x = pack2(o[8]*invL,  o[9]*invL);  u1.y = pack2(o[10]*invL, o[11]*invL);
    u1.z = pack2(o[12]*invL, o[13]*invL); u1.w = pack2(o[14]*invL, o[15]*invL);
    st16(zp, u0);
    st16(zp + 8, u1);
}

// ---------------------------------------------------------------------------
// Output projection GEMM. out[4096][768] = Z @ WOT^T + bO (fp32). BK=64.
// ---------------------------------------------------------------------------
__global__ __launch_bounds__(256, 2) void oproj_gemm(
    const unsigned short* __restrict__ Zin,   // [4096][768] bf16
    const unsigned short* __restrict__ WOT,   // [768][768] bf16 (B^T)
    const float* __restrict__ bO,             // [768] fp32
    float* __restrict__ out)                  // [4096][768] fp32
{
    const int row0 = blockIdx.x * 128;
    const int col0 = blockIdx.y * 128;
    const int t = threadIdx.x;
    const int w = t >> 6, lane = t & 63, quad = lane >> 4, l16 = lane & 15;
    const int wrow0 = (w & 1) * 64, wcol0 = (w >> 1) * 64;

    __shared__ unsigned short Ald[128][72];
    __shared__ unsigned short Bld[128][72];

    f32x4 acc[4][4] = {};

    const int srow = t >> 1;
    const int skh  = (t & 1) * 32;

    const unsigned short* ap = Zin + (size_t)(row0 + srow) * D_ + skh;
    const unsigned short* bp = WOT + (size_t)(col0 + srow) * D_ + skh;

    for (int k0 = 0; k0 < D_; k0 += 64) {
        uint4 a[4], bb[4];
#pragma unroll
        for (int j = 0; j < 4; j++) {
            a[j]  = ld16u(ap + k0 + 8 * j);
            bb[j] = ld16u(bp + k0 + 8 * j);
        }
        __syncthreads();
#pragma unroll
        for (int j = 0; j < 4; j++) {
            st16(&Ald[srow][skh + 8 * j], a[j]);
            st16(&Bld[srow][skh + 8 * j], bb[j]);
        }
        __syncthreads();

        bf16x8 af[4][2], bfm[4][2];
#pragma unroll
        for (int rt = 0; rt < 4; rt++)
#pragma unroll
            for (int c = 0; c < 2; c++)
                af[rt][c] = ld16(&Ald[wrow0 + rt * 16 + l16][c * 32 + quad * 8]);
#pragma unroll
        for (int st = 0; st < 4; st++)
#pragma unroll
            for (int c = 0; c < 2; c++)
                bfm[st][c] = ld16(&Bld[wcol0 + st * 16 + l16][c * 32 + quad * 8]);
#pragma unroll
        for (int rt = 0; rt < 4; rt++)
#pragma unroll
            for (int st = 0; st < 4; st++) {
                acc[rt][st] = __builtin_amdgcn_mfma_f32_16x16x32_bf16(
                    af[rt][0], bfm[st][0], acc[rt][st], 0, 0, 0);
                acc[rt][st] = __builtin_amdgcn_mfma_f32_16x16x32_bf16(
                    af[rt][1], bfm[st][1], acc[rt][st], 0, 0, 0);
            }
    }

#pragma unroll
    for (int st = 0; st < 4; st++) {
        const int c = col0 + wcol0 + st * 16 + l16;
        const float bval = bO[c];
#pragma unroll
        for (int rt = 0; rt < 4; rt++) {
#pragma unroll
            for (int rr = 0; rr < 4; rr++) {
                const int R = row0 + wrow0 + rt * 16 + quad * 4 + rr;
                out[(size_t)R * D_ + c] = acc[rt][st][rr] + bval;
            }
        }
    }
}

// ---------------------------------------------------------------------------
extern "C" void kernel_launch(void* const* d_in, const int* in_sizes, int n_in,
                              void* d_out, int out_size, void* d_ws, size_t ws_size,
                              hipStream_t stream)
{
    const float* x  = (const float*)d_in[0];
    const float* WQ = (const float*)d_in[1];
    const float* bQ = (const float*)d_in[2];
    const float* WK = (const float*)d_in[3];
    const float* bK = (const float*)d_in[4];
    const float* WV = (const float*)d_in[5];
    const float* bV = (const float*)d_in[6];
    const float* WO = (const float*)d_in[7];
    const float* bO = (const float*)d_in[8];
    float* out = (float*)d_out;

    const size_t n = (size_t)B_ * H_ * S_ * M_;     // 3,145,728 elems
    unsigned short* q_ws  = (unsigned short*)d_ws;  // [B,H,S,M] bf16 (scaled)
    unsigned short* k_ws  = q_ws + n;
    unsigned short* v_ws  = k_ws + n;
    unsigned short* z_ws  = v_ws + n;               // [B,S,H*M] bf16
    unsigned short* WT    = z_ws + n;               // [2304][768] bf16
    unsigned short* WOT   = WT + (size_t)NQKV_ * D_;// [768][768] bf16
    float* Opart = (float*)(WOT + (size_t)D_ * D_); // [1920][4096] fp32
    float* mlbuf = Opart + (size_t)TOTCHUNK_ * 4096;// [1920][128] fp32

    prep<<<dim3(288), 256, 0, stream>>>(WQ, WK, WV, WO, WT, WOT);
    qkv_gemm<<<dim3(BS_ / 128, NQKV_ / 128), 256, 0, stream>>>(
        x, WT, bQ, bK, bV, q_ws, k_ws, v_ws);
    attn_split<<<dim3(NCHUNK_, B_ * H_), 256, 0, stream>>>(
        q_ws, k_ws, v_ws, Opart, mlbuf);
    combine<<<dim3(S_ / 64, B_ * H_), 256, 0, stream>>>(Opart, mlbuf, z_ws);
    oproj_gemm<<<dim3(BS_ / 128, D_ / 128), 256, 0, stream>>>(
        z_ws, WOT, bO, out);
}

// Round 7
// 174.736 us; speedup vs baseline: 1.3250x; 1.2227x over previous
//
#include <hip/hip_runtime.h>
#include <hip/hip_bf16.h>
#include <cstdint>
#include <cstddef>

#define B_ 2
#define S_ 2048
#define D_ 768
#define H_ 12
#define M_ 64
#define BS_ (B_ * S_)
#define NQKV_ 2304            // 3 * 768 packed output columns
#define NCHUNK_ 80            // compact chunks per bh (sum of ceil((qt+1)/8))
#define TOTCHUNK_ (24 * NCHUNK_)   // 1920

typedef __attribute__((ext_vector_type(8))) short bf16x8;
typedef __attribute__((ext_vector_type(4))) float f32x4;

__device__ __forceinline__ unsigned short f2bu(float f) {
    __hip_bfloat16 h = __float2bfloat16(f);   // RNE
    unsigned short u;
    __builtin_memcpy(&u, &h, 2);
    return u;
}
__device__ __forceinline__ unsigned pack2(float a, float b) {
    return (unsigned)f2bu(a) | ((unsigned)f2bu(b) << 16);
}

// Alias-safe vector load/store (memcpy => char semantics, still b128 ops).
__device__ __forceinline__ bf16x8 ld16(const unsigned short* p) {
    p = (const unsigned short*)__builtin_assume_aligned(p, 16);
    bf16x8 v; __builtin_memcpy(&v, p, 16); return v;
}
__device__ __forceinline__ uint4 ld16u(const unsigned short* p) {
    p = (const unsigned short*)__builtin_assume_aligned(p, 16);
    uint4 v; __builtin_memcpy(&v, p, 16); return v;
}
__device__ __forceinline__ void st16(unsigned short* p, uint4 v) {
    p = (unsigned short*)__builtin_assume_aligned(p, 16);
    __builtin_memcpy(p, &v, 16);
}
__device__ __forceinline__ void st8(unsigned short* p, uint2 v) {
    p = (unsigned short*)__builtin_assume_aligned(p, 8);
    __builtin_memcpy(p, &v, 8);
}
__device__ __forceinline__ float4 ldf4(const float* p) {
    p = (const float*)__builtin_assume_aligned(p, 16);
    float4 v; __builtin_memcpy(&v, p, 16); return v;
}
// async global->LDS, 16B per lane; lds base must be wave-uniform.
__device__ __forceinline__ void async16(const unsigned short* g, unsigned short* l) {
    __builtin_amdgcn_global_load_lds(
        (const __attribute__((address_space(1))) void*)g,
        (__attribute__((address_space(3))) void*)l, 16, 0, 0);
}
__device__ __forceinline__ void b82f(uint4 u, float* o) {
    o[0] = __uint_as_float(u.x << 16); o[1] = __uint_as_float(u.x & 0xffff0000u);
    o[2] = __uint_as_float(u.y << 16); o[3] = __uint_as_float(u.y & 0xffff0000u);
    o[4] = __uint_as_float(u.z << 16); o[5] = __uint_as_float(u.z & 0xffff0000u);
    o[6] = __uint_as_float(u.w << 16); o[7] = __uint_as_float(u.w & 0xffff0000u);
}

#define NEG_BIG (-3.0e38f)

// ---------------------------------------------------------------------------
// prep: fused weight packing + x conversion.
//  [0,216):    W_Q/K/V -> WT[2304][768] bf16 (B^T)
//  [216,288):  W_O -> WOT[768][768] bf16 (B^T)
//  [288,1056): x fp32 -> xb bf16 (16 elems/thread)
// ---------------------------------------------------------------------------
__global__ void prep(const float* __restrict__ WQ, const float* __restrict__ WK,
                     const float* __restrict__ WV, const float* __restrict__ WO,
                     const float* __restrict__ x,
                     unsigned short* __restrict__ WT,
                     unsigned short* __restrict__ WOT,
                     unsigned short* __restrict__ xb)
{
    const int bx = blockIdx.x;
    if (bx < 216) {
        const int xx = bx % 9, yy = bx / 9;
        const int c  = xx * 256 + threadIdx.x;   // 0..2303
        const int k0 = yy * 32;
        const int which = c / D_;
        const int r = c - which * D_;
        const int h = r >> 6, m = r & 63;
        const float* Wsel = (which == 0) ? WQ : (which == 1) ? WK : WV;
        const float* src = Wsel + (size_t)h * D_ * M_ + m;
        unsigned short* dst = WT + (size_t)c * D_ + k0;
        for (int i = 0; i < 32; i += 8) {
            float wv[8];
#pragma unroll
            for (int j = 0; j < 8; j++) wv[j] = src[(size_t)(k0 + i + j) * M_];
            uint4 pu;
            pu.x = pack2(wv[0], wv[1]); pu.y = pack2(wv[2], wv[3]);
            pu.z = pack2(wv[4], wv[5]); pu.w = pack2(wv[6], wv[7]);
            st16(dst + i, pu);
        }
    } else if (bx < 288) {
        const int b2 = bx - 216;
        const int xx = b2 % 3, yy = b2 / 3;
        const int c  = xx * 256 + threadIdx.x;   // output row d, 0..767
        const int k0 = yy * 32;
        unsigned short* dst = WOT + (size_t)c * D_ + k0;
        for (int i = 0; i < 32; i += 8) {
            float wv[8];
#pragma unroll
            for (int j = 0; j < 8; j++) wv[j] = WO[(size_t)(k0 + i + j) * D_ + c];
            uint4 pu;
            pu.x = pack2(wv[0], wv[1]); pu.y = pack2(wv[2], wv[3]);
            pu.z = pack2(wv[4], wv[5]); pu.w = pack2(wv[6], wv[7]);
            st16(dst + i, pu);
        }
    } else {
        const size_t i = ((size_t)(bx - 288) * 256 + threadIdx.x) * 16;
#pragma unroll
        for (int p = 0; p < 2; p++) {
            float4 a0 = ldf4(x + i + p * 8), a1 = ldf4(x + i + p * 8 + 4);
            uint4 u;
            u.x = pack2(a0.x, a0.y); u.y = pack2(a0.z, a0.w);
            u.z = pack2(a1.x, a1.y); u.w = pack2(a1.z, a1.w);
            st16(xb + i + p * 8, u);
        }
    }
}

// ---------------------------------------------------------------------------
// QKV projection GEMM, m97-style: async global->LDS staging (16B),
// XOR-swizzled unpadded LDS tiles.  C[4096][2304] = xb @ WT^T.
// 128x128 tile, BK=64.  Epilogue: Q/K scatter to [B,H,S,M] (+bias, Q*0.125);
// V written TRANSPOSED to [B,H,M,S].  grid (32,18).
// ---------------------------------------------------------------------------
__global__ __launch_bounds__(256, 2) void qkv_gemm(
    const unsigned short* __restrict__ xb,    // [4096][768] bf16
    const unsigned short* __restrict__ WT,    // [2304][768] bf16
    const float* __restrict__ bQ, const float* __restrict__ bK,
    const float* __restrict__ bV,
    unsigned short* __restrict__ qo, unsigned short* __restrict__ ko,
    unsigned short* __restrict__ vt)
{
    const int row0 = blockIdx.x * 128;
    const int col0 = blockIdx.y * 128;
    const int t = threadIdx.x;
    const int w = t >> 6, lane = t & 63, quad = lane >> 4, l16 = lane & 15;
    const int wrow0 = (w & 1) * 64, wcol0 = (w >> 1) * 64;

    __shared__ unsigned short Alds[128 * 64];   // unpadded, swizzled
    __shared__ unsigned short Blds[128 * 64];

    f32x4 acc[4][4] = {};

    // DMA source pointers: chunk ci = w*256 + q*64 + lane
    const unsigned short* asrc[4];
    const unsigned short* bsrc[4];
    int ldsoff[4];
#pragma unroll
    for (int q = 0; q < 4; q++) {
        const int cq = w * 256 + q * 64 + lane;
        const int row = cq >> 3, c = cq & 7;
        const int cs = c ^ (row & 7);
        asrc[q] = xb + (size_t)(row0 + row) * D_ + cs * 8;
        bsrc[q] = WT + (size_t)(col0 + row) * D_ + cs * 8;
        ldsoff[q] = (w * 256 + q * 64) * 8;   // wave-uniform
    }
    const int swz = (l16 & 7);

    for (int k0 = 0; k0 < D_; k0 += 64) {
#pragma unroll
        for (int q = 0; q < 4; q++) async16(asrc[q] + k0, Alds + ldsoff[q]);
#pragma unroll
        for (int q = 0; q < 4; q++) async16(bsrc[q] + k0, Blds + ldsoff[q]);
        __syncthreads();   // drains vmcnt -> DMA landed

        bf16x8 af[4][2], bfm[4][2];
#pragma unroll
        for (int rt = 0; rt < 4; rt++) {
            const int row = wrow0 + rt * 16 + l16;
#pragma unroll
            for (int hh = 0; hh < 2; hh++)
                af[rt][hh] = ld16(&Alds[row * 64 + ((hh * 4 + quad) ^ swz) * 8]);
        }
#pragma unroll
        for (int st = 0; st < 4; st++) {
            const int row = wcol0 + st * 16 + l16;
#pragma unroll
            for (int hh = 0; hh < 2; hh++)
                bfm[st][hh] = ld16(&Blds[row * 64 + ((hh * 4 + quad) ^ swz) * 8]);
        }
#pragma unroll
        for (int rt = 0; rt < 4; rt++)
#pragma unroll
            for (int st = 0; st < 4; st++) {
                acc[rt][st] = __builtin_amdgcn_mfma_f32_16x16x32_bf16(
                    af[rt][0], bfm[st][0], acc[rt][st], 0, 0, 0);
                acc[rt][st] = __builtin_amdgcn_mfma_f32_16x16x32_bf16(
                    af[rt][1], bfm[st][1], acc[rt][st], 0, 0, 0);
            }
        __syncthreads();   // all frag reads done before next DMA overwrites
    }

    const int which = col0 / D_;                 // tile never spans a matrix
    const int colin = col0 - which * D_;

    if (which < 2) {
        const float* bias = (which == 0) ? bQ : bK;
        unsigned short* outp = (which == 0) ? qo : ko;
        const float scale = (which == 0) ? 0.125f : 1.0f;
#pragma unroll
        for (int st = 0; st < 4; st++) {
            const int cl = colin + wcol0 + st * 16 + l16;
            const int h = cl >> 6, m = cl & 63;
            const float bval = bias[cl];
#pragma unroll
            for (int rt = 0; rt < 4; rt++)
#pragma unroll
                for (int rr = 0; rr < 4; rr++) {
                    const int R = row0 + wrow0 + rt * 16 + quad * 4 + rr;
                    const int bb = R >> 11, s = R & (S_ - 1);
                    outp[(((size_t)bb * H_ + h) * S_ + s) * M_ + m] =
                        f2bu((acc[rt][st][rr] + bval) * scale);
                }
        }
    } else {
        // V -> V^T [B,H,M,S]: 4 consecutive s per lane -> packed 8B store
#pragma unroll
        for (int st = 0; st < 4; st++) {
            const int cl = colin + wcol0 + st * 16 + l16;
            const int h = cl >> 6, m = cl & 63;
            const float bval = bV[cl];
#pragma unroll
            for (int rt = 0; rt < 4; rt++) {
                const int R0 = row0 + wrow0 + rt * 16 + quad * 4;
                const int bb = R0 >> 11, s0 = R0 & (S_ - 1);
                uint2 v;
                v.x = pack2(acc[rt][st][0] + bval, acc[rt][st][1] + bval);
                v.y = pack2(acc[rt][st][2] + bval, acc[rt][st][3] + bval);
                st8(&vt[(((size_t)bb * H_ + h) * M_ + m) * S_ + s0], v);
            }
        }
    }
}

// ---------------------------------------------------------------------------
// Split-K causal flash attention.  grid (80, 24).  64q x up to 512 keys
// (<=4 iters of 128).  K staged from [B,H,S,M]; V staged from pre-transposed
// [B,H,M,S] -- both fully vectorized, register-prefetched.
// Partials (unnormalized O, bf16) + (m,l) fp32 to workspace.
// ---------------------------------------------------------------------------
struct StageRegs { uint4 ka[4]; uint4 va[4]; };

__device__ __forceinline__ void load_tile(const unsigned short* kb,
                                          const unsigned short* vb,
                                          int t, StageRegs& s)
{
#pragma unroll
    for (int q = 0; q < 4; q++) {
        const int ci = q * 256 + t;
        s.ka[q] = ld16u(kb + (size_t)(ci >> 3) * M_ + (ci & 7) * 8);
    }
#pragma unroll
    for (int q = 0; q < 4; q++) {
        const int ci = q * 256 + t;
        s.va[q] = ld16u(vb + (size_t)(ci >> 4) * S_ + (ci & 15) * 8);
    }
}

__global__ __launch_bounds__(256, 3) void attn_split(
    const unsigned short* __restrict__ Q,   // [B,H,S,M] bf16 (scaled)
    const unsigned short* __restrict__ Kin, // [B,H,S,M] bf16
    const unsigned short* __restrict__ Vt,  // [B,H,M,S] bf16 (transposed)
    unsigned short* __restrict__ Opart,     // [1920][64][64] bf16
    float* __restrict__ ml)                 // [1920][128] fp32 (m then l)
{
    const int xx = blockIdx.x;              // 0..79 compact (qt, c)
    const int bh = blockIdx.y;

    int qt, c, nc;
    if (xx < 8)       { qt = xx; c = 0; nc = 1; }
    else if (xx < 24) { int u = xx - 8;  qt = 8  + (u >> 1); c = u & 1;  nc = 2; }
    else if (xx < 48) { int u = xx - 24; qt = 16 + u / 3;    c = u % 3;  nc = 3; }
    else              { int u = xx - 48; qt = 24 + (u >> 2); c = u & 3;  nc = 4; }

    const int ci     = bh * NCHUNK_ + xx;
    const int kbeg   = c * 512;
    const int keyend = min((qt + 1) * 64, kbeg + 512);
    const int iters  = (keyend - kbeg + 127) >> 7;
    const bool lastchunk = (c == nc - 1);

    const int t = threadIdx.x;
    const int wave = t >> 6, lane = t & 63, quad = lane >> 4, l16 = lane & 15;

    const unsigned short* Qb  = Q   + ((size_t)bh * S_ + qt * 64) * M_;
    const unsigned short* Kb  = Kin + (size_t)bh * S_ * M_;
    const unsigned short* VtB = Vt  + (size_t)bh * M_ * S_;

    __shared__ unsigned short Klds[128][72];    // [key][feat]
    __shared__ unsigned short Vlds[64][136];    // [feat][key]
    __shared__ unsigned short Plds[4][16][132]; // per-wave [qrow][key]

    bf16x8 qf[2];
    {
        const unsigned short* qrow = Qb + (size_t)(wave * 16 + l16) * M_;
        qf[0] = ld16(qrow + quad * 8);
        qf[1] = ld16(qrow + 32 + quad * 8);
    }

    f32x4 o_acc[4] = {};
    float mrow[4] = {NEG_BIG, NEG_BIG, NEG_BIG, NEG_BIG};
    float lrow[4] = {0.f, 0.f, 0.f, 0.f};

    StageRegs sr;
    load_tile(Kb + (size_t)kbeg * M_, VtB + kbeg, t, sr);

    for (int it = 0; it < iters; it++) {
        __syncthreads();
#pragma unroll
        for (int q = 0; q < 4; q++) {
            const int cq = q * 256 + t;
            st16(&Klds[cq >> 3][(cq & 7) * 8], sr.ka[q]);
        }
#pragma unroll
        for (int q = 0; q < 4; q++) {
            const int cq = q * 256 + t;
            st16(&Vlds[cq >> 4][(cq & 15) * 8], sr.va[q]);
        }
        __syncthreads();

        if (it + 1 < iters) {   // prefetch next tile into registers
            const int key1 = kbeg + (it + 1) * 128;
            load_tile(Kb + (size_t)key1 * M_, VtB + key1, t, sr);
        }

        // S = Q K^T over 128 keys (8 column strips)
        f32x4 s_acc[8];
#pragma unroll
        for (int st = 0; st < 8; st++) {
            f32x4 z4 = {0.f, 0.f, 0.f, 0.f};
            bf16x8 kb0 = ld16(&Klds[st * 16 + l16][quad * 8]);
            bf16x8 kb1 = ld16(&Klds[st * 16 + l16][32 + quad * 8]);
            z4 = __builtin_amdgcn_mfma_f32_16x16x32_bf16(qf[0], kb0, z4, 0, 0, 0);
            z4 = __builtin_amdgcn_mfma_f32_16x16x32_bf16(qf[1], kb1, z4, 0, 0, 0);
            s_acc[st] = z4;
        }

        if (lastchunk && it == iters - 1) {
            const int key0 = kbeg + it * 128;
            const int qrow = qt * 64 + wave * 16 + quad * 4;
#pragma unroll
            for (int st = 0; st < 8; st++)
#pragma unroll
                for (int r = 0; r < 4; r++)
                    if (key0 + st * 16 + l16 > qrow + r)
                        s_acc[st][r] = -1e30f;
        }

        float rmax[4];
#pragma unroll
        for (int r = 0; r < 4; r++) {
            float m0 = fmaxf(fmaxf(s_acc[0][r], s_acc[1][r]),
                             fmaxf(s_acc[2][r], s_acc[3][r]));
            float m1 = fmaxf(fmaxf(s_acc[4][r], s_acc[5][r]),
                             fmaxf(s_acc[6][r], s_acc[7][r]));
            rmax[r] = fmaxf(m0, m1);
        }
#pragma unroll
        for (int off = 1; off < 16; off <<= 1)
#pragma unroll
            for (int r = 0; r < 4; r++)
                rmax[r] = fmaxf(rmax[r], __shfl_xor(rmax[r], off, 64));

        float mnew[4], alpha[4];
#pragma unroll
        for (int r = 0; r < 4; r++) {
            mnew[r]  = fmaxf(mrow[r], rmax[r]);
            alpha[r] = __expf(mrow[r] - mnew[r]);
            mrow[r]  = mnew[r];
        }

        float psum[4] = {0.f, 0.f, 0.f, 0.f};
#pragma unroll
        for (int st = 0; st < 8; st++) {
#pragma unroll
            for (int r = 0; r < 4; r++) {
                float p = __expf(s_acc[st][r] - mnew[r]);
                psum[r] += p;
                Plds[wave][quad * 4 + r][st * 16 + l16] = f2bu(p);
            }
        }
#pragma unroll
        for (int off = 1; off < 16; off <<= 1)
#pragma unroll
            for (int r = 0; r < 4; r++)
                psum[r] += __shfl_xor(psum[r], off, 64);

#pragma unroll
        for (int r = 0; r < 4; r++) lrow[r] = lrow[r] * alpha[r] + psum[r];
#pragma unroll
        for (int st = 0; st < 4; st++)
#pragma unroll
            for (int r = 0; r < 4; r++) o_acc[st][r] *= alpha[r];

        __syncthreads();   // order the P round-trip

        bf16x8 pf[4];
#pragma unroll
        for (int cc = 0; cc < 4; cc++)
            pf[cc] = ld16(&Plds[wave][l16][cc * 32 + quad * 8]);
#pragma unroll
        for (int st = 0; st < 4; st++) {
#pragma unroll
            for (int cc = 0; cc < 4; cc++) {
                bf16x8 vb = ld16(&Vlds[st * 16 + l16][cc * 32 + quad * 8]);
                o_acc[st] = __builtin_amdgcn_mfma_f32_16x16x32_bf16(
                    pf[cc], vb, o_acc[st], 0, 0, 0);
            }
        }
    }

    // write unnormalized partials (bf16)
    unsigned short* Op = Opart + (size_t)ci * 4096;
#pragma unroll
    for (int st = 0; st < 4; st++)
#pragma unroll
        for (int r = 0; r < 4; r++) {
            const int q = wave * 16 + quad * 4 + r;
            Op[q * 64 + st * 16 + l16] = f2bu(o_acc[st][r]);
        }
    if (l16 == 0) {
#pragma unroll
        for (int r = 0; r < 4; r++) {
            const int q = wave * 16 + quad * 4 + r;
            ml[(size_t)ci * 128 + q]      = mrow[r];
            ml[(size_t)ci * 128 + 64 + q] = lrow[r];
        }
    }
}

// ---------------------------------------------------------------------------
// Combine: merge <=4 bf16 partials per (bh, qt) into Z [B,S,H*M] bf16.
// grid (32, 24).  Thread t: q=t>>2, feats (t&3)*16..+15.
// ---------------------------------------------------------------------------
__global__ void combine(const unsigned short* __restrict__ Opart,
                        const float* __restrict__ ml,
                        unsigned short* __restrict__ Z)
{
    const int qt = blockIdx.x, bh = blockIdx.y;
    const int b = bh / H_, h = bh - b * H_;
    const int g = qt >> 3, r7 = qt & 7;
    const int nc = g + 1;
    const int base = bh * NCHUNK_ + qt + 4 * g * (g - 1) + r7 * g;

    const int t = threadIdx.x;
    const int q = t >> 2, fs = (t & 3) * 16;

    float m_c[4], l_c[4];
    float M = NEG_BIG;
    for (int c = 0; c < nc; c++) {
        m_c[c] = ml[(size_t)(base + c) * 128 + q];
        l_c[c] = ml[(size_t)(base + c) * 128 + 64 + q];
        M = fmaxf(M, m_c[c]);
    }
    float L = 0.f;
    float w_c[4];
    for (int c = 0; c < nc; c++) {
        w_c[c] = __expf(m_c[c] - M);
        L += l_c[c] * w_c[c];
    }
    const float invL = 1.0f / L;

    float o[16] = {};
    for (int c = 0; c < nc; c++) {
        const unsigned short* op =
            Opart + (size_t)(base + c) * 4096 + q * 64 + fs;
        const float wc = w_c[c];
        float f[8];
        b82f(ld16u(op), f);
#pragma unroll
        for (int j = 0; j < 8; j++) o[j] += wc * f[j];
        b82f(ld16u(op + 8), f);
#pragma unroll
        for (int j = 0; j < 8; j++) o[8 + j] += wc * f[j];
    }

    unsigned short* zp =
        Z + ((size_t)b * S_ + qt * 64 + q) * (H_ * M_) + h * M_ + fs;
    uint4 u0, u1;
    u0.x = pack2(o[0]*invL,  o[1]*invL);  u0.y = pack2(o[2]*invL,  o[3]*invL);
    u0.z = pack2(o[4]*invL,  o[5]*invL);  u0.w = pack2(o[6]*invL,  o[7]*invL);
    u1.x = pack2(o[8]*invL,  o[9]*invL);  u1.y = pack2(o[10]*invL, o[11]*invL);
    u1.z = pack2(o[12]*invL, o[13]*invL); u1.w = pack2(o[14]*invL, o[15]*invL);
    st16(zp, u0);
    st16(zp + 8, u1);
}

// ---------------------------------------------------------------------------
// Output projection GEMM, same async-staged structure. out = Z @ WOT^T + bO.
// grid (32,6).
// ---------------------------------------------------------------------------
__global__ __launch_bounds__(256, 2) void oproj_gemm(
    const unsigned short* __restrict__ Zin,   // [4096][768] bf16
    const unsigned short* __restrict__ WOT,   // [768][768] bf16 (B^T)
    const float* __restrict__ bO,             // [768] fp32
    float* __restrict__ out)                  // [4096][768] fp32
{
    const int row0 = blockIdx.x * 128;
    const int col0 = blockIdx.y * 128;
    const int t = threadIdx.x;
    const int w = t >> 6, lane = t & 63, quad = lane >> 4, l16 = lane & 15;
    const int wrow0 = (w & 1) * 64, wcol0 = (w >> 1) * 64;

    __shared__ unsigned short Alds[128 * 64];
    __shared__ unsigned short Blds[128 * 64];

    f32x4 acc[4][4] = {};

    const unsigned short* asrc[4];
    const unsigned short* bsrc[4];
    int ldsoff[4];
#pragma unroll
    for (int q = 0; q < 4; q++) {
        const int cq = w * 256 + q * 64 + lane;
        const int row = cq >> 3, c = cq & 7;
        const int cs = c ^ (row & 7);
        asrc[q] = Zin + (size_t)(row0 + row) * D_ + cs * 8;
        bsrc[q] = WOT + (size_t)(col0 + row) * D_ + cs * 8;
        ldsoff[q] = (w * 256 + q * 64) * 8;
    }
    const int swz = (l16 & 7);

    for (int k0 = 0; k0 < D_; k0 += 64) {
#pragma unroll
        for (int q = 0; q < 4; q++) async16(asrc[q] + k0, Alds + ldsoff[q]);
#pragma unroll
        for (int q = 0; q < 4; q++) async16(bsrc[q] + k0, Blds + ldsoff[q]);
        __syncthreads();

        bf16x8 af[4][2], bfm[4][2];
#pragma unroll
        for (int rt = 0; rt < 4; rt++) {
            const int row = wrow0 + rt * 16 + l16;
#pragma unroll
            for (int hh = 0; hh < 2; hh++)
                af[rt][hh] = ld16(&Alds[row * 64 + ((hh * 4 + quad) ^ swz) * 8]);
        }
#pragma unroll
        for (int st = 0; st < 4; st++) {
            const int row = wcol0 + st * 16 + l16;
#pragma unroll
            for (int hh = 0; hh < 2; hh++)
                bfm[st][hh] = ld16(&Blds[row * 64 + ((hh * 4 + quad) ^ swz) * 8]);
        }
#pragma unroll
        for (int rt = 0; rt < 4; rt++)
#pragma unroll
            for (int st = 0; st < 4; st++) {
                acc[rt][st] = __builtin_amdgcn_mfma_f32_16x16x32_bf16(
                    af[rt][0], bfm[st][0], acc[rt][st], 0, 0, 0);
                acc[rt][st] = __builtin_amdgcn_mfma_f32_16x16x32_bf16(
                    af[rt][1], bfm[st][1], acc[rt][st], 0, 0, 0);
            }
        __syncthreads();
    }

#pragma unroll
    for (int st = 0; st < 4; st++) {
        const int c = col0 + wcol0 + st * 16 + l16;
        const float bval = bO[c];
#pragma unroll
        for (int rt = 0; rt < 4; rt++)
#pragma unroll
            for (int rr = 0; rr < 4; rr++) {
                const int R = row0 + wrow0 + rt * 16 + quad * 4 + rr;
                out[(size_t)R * D_ + c] = acc[rt][st][rr] + bval;
            }
    }
}

// ---------------------------------------------------------------------------
extern "C" void kernel_launch(void* const* d_in, const int* in_sizes, int n_in,
                              void* d_out, int out_size, void* d_ws, size_t ws_size,
                              hipStream_t stream)
{
    const float* x  = (const float*)d_in[0];
    const float* WQ = (const float*)d_in[1];
    const float* bQ = (const float*)d_in[2];
    const float* WK = (const float*)d_in[3];
    const float* bK = (const float*)d_in[4];
    const float* WV = (const float*)d_in[5];
    const float* bV = (const float*)d_in[6];
    const float* WO = (const float*)d_in[7];
    const float* bO = (const float*)d_in[8];
    float* out = (float*)d_out;

    const size_t n = (size_t)B_ * H_ * S_ * M_;     // 3,145,728 elems
    unsigned short* q_ws  = (unsigned short*)d_ws;  // [B,H,S,M] bf16 (scaled)
    unsigned short* k_ws  = q_ws + n;               // [B,H,S,M]
    unsigned short* vt_ws = k_ws + n;               // [B,H,M,S] (transposed!)
    unsigned short* z_ws  = vt_ws + n;              // [B,S,H*M]
    unsigned short* WT    = z_ws + n;               // [2304][768]
    unsigned short* WOT   = WT + (size_t)NQKV_ * D_;// [768][768]
    unsigned short* xb    = WOT + (size_t)D_ * D_;  // [4096][768]
    unsigned short* Opart = xb + (size_t)BS_ * D_;  // [1920][4096] bf16
    float* mlbuf = (float*)(Opart + (size_t)TOTCHUNK_ * 4096); // [1920][128]

    prep<<<dim3(1056), 256, 0, stream>>>(WQ, WK, WV, WO, x, WT, WOT, xb);
    qkv_gemm<<<dim3(BS_ / 128, NQKV_ / 128), 256, 0, stream>>>(
        xb, WT, bQ, bK, bV, q_ws, k_ws, vt_ws);
    attn_split<<<dim3(NCHUNK_, B_ * H_), 256, 0, stream>>>(
        q_ws, k_ws, vt_ws, Opart, mlbuf);
    combine<<<dim3(S_ / 64, B_ * H_), 256, 0, stream>>>(Opart, mlbuf, z_ws);
    oproj_gemm<<<dim3(BS_ / 128, D_ / 128), 256, 0, stream>>>(
        z_ws, WOT, bO, out);
}

// Round 8
// 166.108 us; speedup vs baseline: 1.3938x; 1.0519x over previous
//
#include <hip/hip_runtime.h>
#include <hip/hip_bf16.h>
#include <cstdint>
#include <cstddef>

#define B_ 2
#define S_ 2048
#define D_ 768
#define H_ 12
#define M_ 64
#define BS_ (B_ * S_)
#define NQKV_ 2304            // 3 * 768 packed output columns
#define NCHUNK_ 80            // compact chunks per bh (sum of ceil((qt+1)/8))
#define TOTCHUNK_ (24 * NCHUNK_)   // 1920

typedef __attribute__((ext_vector_type(8))) short bf16x8;
typedef __attribute__((ext_vector_type(4))) float f32x4;

__device__ __forceinline__ unsigned short f2bu(float f) {
    __hip_bfloat16 h = __float2bfloat16(f);   // RNE
    unsigned short u;
    __builtin_memcpy(&u, &h, 2);
    return u;
}
__device__ __forceinline__ unsigned pack2(float a, float b) {
    return (unsigned)f2bu(a) | ((unsigned)f2bu(b) << 16);
}

// Alias-safe vector load/store (memcpy => char semantics, still b128 ops).
__device__ __forceinline__ bf16x8 ld16(const unsigned short* p) {
    p = (const unsigned short*)__builtin_assume_aligned(p, 16);
    bf16x8 v; __builtin_memcpy(&v, p, 16); return v;
}
__device__ __forceinline__ uint4 ld16u(const unsigned short* p) {
    p = (const unsigned short*)__builtin_assume_aligned(p, 16);
    uint4 v; __builtin_memcpy(&v, p, 16); return v;
}
__device__ __forceinline__ void st16(unsigned short* p, uint4 v) {
    p = (unsigned short*)__builtin_assume_aligned(p, 16);
    __builtin_memcpy(p, &v, 16);
}
__device__ __forceinline__ void st8(unsigned short* p, uint2 v) {
    p = (unsigned short*)__builtin_assume_aligned(p, 8);
    __builtin_memcpy(p, &v, 8);
}
__device__ __forceinline__ float4 ldf4(const float* p) {
    p = (const float*)__builtin_assume_aligned(p, 16);
    float4 v; __builtin_memcpy(&v, p, 16); return v;
}
// async global->LDS, 16B per lane; lds base must be wave-uniform.
__device__ __forceinline__ void async16(const unsigned short* g, unsigned short* l) {
    __builtin_amdgcn_global_load_lds(
        (const __attribute__((address_space(1))) void*)g,
        (__attribute__((address_space(3))) void*)l, 16, 0, 0);
}
__device__ __forceinline__ void b82f(uint4 u, float* o) {
    o[0] = __uint_as_float(u.x << 16); o[1] = __uint_as_float(u.x & 0xffff0000u);
    o[2] = __uint_as_float(u.y << 16); o[3] = __uint_as_float(u.y & 0xffff0000u);
    o[4] = __uint_as_float(u.z << 16); o[5] = __uint_as_float(u.z & 0xffff0000u);
    o[6] = __uint_as_float(u.w << 16); o[7] = __uint_as_float(u.w & 0xffff0000u);
}

#define NEG_BIG (-3.0e38f)

// ---------------------------------------------------------------------------
// prep: fused weight packing + x conversion.
// ---------------------------------------------------------------------------
__global__ void prep(const float* __restrict__ WQ, const float* __restrict__ WK,
                     const float* __restrict__ WV, const float* __restrict__ WO,
                     const float* __restrict__ x,
                     unsigned short* __restrict__ WT,
                     unsigned short* __restrict__ WOT,
                     unsigned short* __restrict__ xb)
{
    const int bx = blockIdx.x;
    if (bx < 216) {
        const int xx = bx % 9, yy = bx / 9;
        const int c  = xx * 256 + threadIdx.x;   // 0..2303
        const int k0 = yy * 32;
        const int which = c / D_;
        const int r = c - which * D_;
        const int h = r >> 6, m = r & 63;
        const float* Wsel = (which == 0) ? WQ : (which == 1) ? WK : WV;
        const float* src = Wsel + (size_t)h * D_ * M_ + m;
        unsigned short* dst = WT + (size_t)c * D_ + k0;
        for (int i = 0; i < 32; i += 8) {
            float wv[8];
#pragma unroll
            for (int j = 0; j < 8; j++) wv[j] = src[(size_t)(k0 + i + j) * M_];
            uint4 pu;
            pu.x = pack2(wv[0], wv[1]); pu.y = pack2(wv[2], wv[3]);
            pu.z = pack2(wv[4], wv[5]); pu.w = pack2(wv[6], wv[7]);
            st16(dst + i, pu);
        }
    } else if (bx < 288) {
        const int b2 = bx - 216;
        const int xx = b2 % 3, yy = b2 / 3;
        const int c  = xx * 256 + threadIdx.x;   // output row d, 0..767
        const int k0 = yy * 32;
        unsigned short* dst = WOT + (size_t)c * D_ + k0;
        for (int i = 0; i < 32; i += 8) {
            float wv[8];
#pragma unroll
            for (int j = 0; j < 8; j++) wv[j] = WO[(size_t)(k0 + i + j) * D_ + c];
            uint4 pu;
            pu.x = pack2(wv[0], wv[1]); pu.y = pack2(wv[2], wv[3]);
            pu.z = pack2(wv[4], wv[5]); pu.w = pack2(wv[6], wv[7]);
            st16(dst + i, pu);
        }
    } else {
        const size_t i = ((size_t)(bx - 288) * 256 + threadIdx.x) * 16;
#pragma unroll
        for (int p = 0; p < 2; p++) {
            float4 a0 = ldf4(x + i + p * 8), a1 = ldf4(x + i + p * 8 + 4);
            uint4 u;
            u.x = pack2(a0.x, a0.y); u.y = pack2(a0.z, a0.w);
            u.z = pack2(a1.x, a1.y); u.w = pack2(a1.z, a1.w);
            st16(xb + i + p * 8, u);
        }
    }
}

// ---------------------------------------------------------------------------
// QKV projection GEMM (async LDS staging, XOR-swizzled).  grid (32,18).
// ---------------------------------------------------------------------------
__global__ __launch_bounds__(256, 2) void qkv_gemm(
    const unsigned short* __restrict__ xb,    // [4096][768] bf16
    const unsigned short* __restrict__ WT,    // [2304][768] bf16
    const float* __restrict__ bQ, const float* __restrict__ bK,
    const float* __restrict__ bV,
    unsigned short* __restrict__ qo, unsigned short* __restrict__ ko,
    unsigned short* __restrict__ vt)
{
    const int row0 = blockIdx.x * 128;
    const int col0 = blockIdx.y * 128;
    const int t = threadIdx.x;
    const int w = t >> 6, lane = t & 63, quad = lane >> 4, l16 = lane & 15;
    const int wrow0 = (w & 1) * 64, wcol0 = (w >> 1) * 64;

    __shared__ unsigned short Alds[128 * 64];   // unpadded, swizzled
    __shared__ unsigned short Blds[128 * 64];

    f32x4 acc[4][4] = {};

    const unsigned short* asrc[4];
    const unsigned short* bsrc[4];
    int ldsoff[4];
#pragma unroll
    for (int q = 0; q < 4; q++) {
        const int cq = w * 256 + q * 64 + lane;
        const int row = cq >> 3, c = cq & 7;
        const int cs = c ^ (row & 7);
        asrc[q] = xb + (size_t)(row0 + row) * D_ + cs * 8;
        bsrc[q] = WT + (size_t)(col0 + row) * D_ + cs * 8;
        ldsoff[q] = (w * 256 + q * 64) * 8;   // wave-uniform
    }
    const int swz = (l16 & 7);

    for (int k0 = 0; k0 < D_; k0 += 64) {
#pragma unroll
        for (int q = 0; q < 4; q++) async16(asrc[q] + k0, Alds + ldsoff[q]);
#pragma unroll
        for (int q = 0; q < 4; q++) async16(bsrc[q] + k0, Blds + ldsoff[q]);
        __syncthreads();   // drains vmcnt -> DMA landed

        bf16x8 af[4][2], bfm[4][2];
#pragma unroll
        for (int rt = 0; rt < 4; rt++) {
            const int row = wrow0 + rt * 16 + l16;
#pragma unroll
            for (int hh = 0; hh < 2; hh++)
                af[rt][hh] = ld16(&Alds[row * 64 + ((hh * 4 + quad) ^ swz) * 8]);
        }
#pragma unroll
        for (int st = 0; st < 4; st++) {
            const int row = wcol0 + st * 16 + l16;
#pragma unroll
            for (int hh = 0; hh < 2; hh++)
                bfm[st][hh] = ld16(&Blds[row * 64 + ((hh * 4 + quad) ^ swz) * 8]);
        }
#pragma unroll
        for (int rt = 0; rt < 4; rt++)
#pragma unroll
            for (int st = 0; st < 4; st++) {
                acc[rt][st] = __builtin_amdgcn_mfma_f32_16x16x32_bf16(
                    af[rt][0], bfm[st][0], acc[rt][st], 0, 0, 0);
                acc[rt][st] = __builtin_amdgcn_mfma_f32_16x16x32_bf16(
                    af[rt][1], bfm[st][1], acc[rt][st], 0, 0, 0);
            }
        __syncthreads();
    }

    const int which = col0 / D_;
    const int colin = col0 - which * D_;

    if (which < 2) {
        const float* bias = (which == 0) ? bQ : bK;
        unsigned short* outp = (which == 0) ? qo : ko;
        const float scale = (which == 0) ? 0.125f : 1.0f;
#pragma unroll
        for (int st = 0; st < 4; st++) {
            const int cl = colin + wcol0 + st * 16 + l16;
            const int h = cl >> 6, m = cl & 63;
            const float bval = bias[cl];
#pragma unroll
            for (int rt = 0; rt < 4; rt++)
#pragma unroll
                for (int rr = 0; rr < 4; rr++) {
                    const int R = row0 + wrow0 + rt * 16 + quad * 4 + rr;
                    const int bb = R >> 11, s = R & (S_ - 1);
                    outp[(((size_t)bb * H_ + h) * S_ + s) * M_ + m] =
                        f2bu((acc[rt][st][rr] + bval) * scale);
                }
        }
    } else {
#pragma unroll
        for (int st = 0; st < 4; st++) {
            const int cl = colin + wcol0 + st * 16 + l16;
            const int h = cl >> 6, m = cl & 63;
            const float bval = bV[cl];
#pragma unroll
            for (int rt = 0; rt < 4; rt++) {
                const int R0 = row0 + wrow0 + rt * 16 + quad * 4;
                const int bb = R0 >> 11, s0 = R0 & (S_ - 1);
                uint2 v;
                v.x = pack2(acc[rt][st][0] + bval, acc[rt][st][1] + bval);
                v.y = pack2(acc[rt][st][2] + bval, acc[rt][st][3] + bval);
                st8(&vt[(((size_t)bb * H_ + h) * M_ + m) * S_ + s0], v);
            }
        }
    }
}

// ---------------------------------------------------------------------------
// Split-K causal flash attention, TRANSPOSED compute space.
// grid (80, 24).  64q x up to 512 keys (<=4 iters of 128).
//   S^T = K Q^T  (operand-swapped MFMA; lane owns column q = l16)
//   per-lane scalar online softmax (2 shuffles instead of 16)
//   P packed b64 into Plds[q][key]; O^T = V^T P^T.
// ---------------------------------------------------------------------------
struct StageRegs { uint4 ka[4]; uint4 va[4]; };

__device__ __forceinline__ void load_tile(const unsigned short* kb,
                                          const unsigned short* vb,
                                          int t, StageRegs& s)
{
#pragma unroll
    for (int q = 0; q < 4; q++) {
        const int ci = q * 256 + t;
        s.ka[q] = ld16u(kb + (size_t)(ci >> 3) * M_ + (ci & 7) * 8);
    }
#pragma unroll
    for (int q = 0; q < 4; q++) {
        const int ci = q * 256 + t;
        s.va[q] = ld16u(vb + (size_t)(ci >> 4) * S_ + (ci & 15) * 8);
    }
}

__global__ __launch_bounds__(256, 3) void attn_split(
    const unsigned short* __restrict__ Q,   // [B,H,S,M] bf16 (scaled)
    const unsigned short* __restrict__ Kin, // [B,H,S,M] bf16
    const unsigned short* __restrict__ Vt,  // [B,H,M,S] bf16 (transposed)
    unsigned short* __restrict__ Opart,     // [1920][64][64] bf16
    float* __restrict__ ml)                 // [1920][128] fp32 (m then l)
{
    const int xx = blockIdx.x;              // 0..79 compact (qt, c)
    const int bh = blockIdx.y;

    int qt, c, nc;
    if (xx < 8)       { qt = xx; c = 0; nc = 1; }
    else if (xx < 24) { int u = xx - 8;  qt = 8  + (u >> 1); c = u & 1;  nc = 2; }
    else if (xx < 48) { int u = xx - 24; qt = 16 + u / 3;    c = u % 3;  nc = 3; }
    else              { int u = xx - 48; qt = 24 + (u >> 2); c = u & 3;  nc = 4; }

    const int ci     = bh * NCHUNK_ + xx;
    const int kbeg   = c * 512;
    const int keyend = min((qt + 1) * 64, kbeg + 512);
    const int iters  = (keyend - kbeg + 127) >> 7;
    const bool lastchunk = (c == nc - 1);

    const int t = threadIdx.x;
    const int wave = t >> 6, lane = t & 63, quad = lane >> 4, l16 = lane & 15;

    const unsigned short* Qb  = Q   + ((size_t)bh * S_ + qt * 64) * M_;
    const unsigned short* Kb  = Kin + (size_t)bh * S_ * M_;
    const unsigned short* VtB = Vt  + (size_t)bh * M_ * S_;

    __shared__ unsigned short Klds[128][72];    // [key][feat]
    __shared__ unsigned short Vlds[64][136];    // [feat][key]
    __shared__ unsigned short Plds[4][16][136]; // per-wave [q(l16)][key]

    bf16x8 qf[2];   // B-frag of Q^T: lane supplies Q[q=l16(+wave*16)][feat=quad*8+j]
    {
        const unsigned short* qrow = Qb + (size_t)(wave * 16 + l16) * M_;
        qf[0] = ld16(qrow + quad * 8);
        qf[1] = ld16(qrow + 32 + quad * 8);
    }

    f32x4 o_acc[4] = {};     // O^T: [feat strip][r] at col q=l16
    float mrow = NEG_BIG, lrow = 0.f;   // per-lane (column q)

    StageRegs sr;
    load_tile(Kb + (size_t)kbeg * M_, VtB + kbeg, t, sr);

    for (int it = 0; it < iters; it++) {
        __syncthreads();
#pragma unroll
        for (int q = 0; q < 4; q++) {
            const int cq = q * 256 + t;
            st16(&Klds[cq >> 3][(cq & 7) * 8], sr.ka[q]);
        }
#pragma unroll
        for (int q = 0; q < 4; q++) {
            const int cq = q * 256 + t;
            st16(&Vlds[cq >> 4][(cq & 15) * 8], sr.va[q]);
        }
        __syncthreads();

        if (it + 1 < iters) {   // prefetch next tile into registers
            const int key1 = kbeg + (it + 1) * 128;
            load_tile(Kb + (size_t)key1 * M_, VtB + key1, t, sr);
        }

        // S^T = K Q^T over 128 keys (8 row strips of 16 keys)
        f32x4 s_acc[8];
#pragma unroll
        for (int st = 0; st < 8; st++) {
            f32x4 z4 = {0.f, 0.f, 0.f, 0.f};
            bf16x8 kb0 = ld16(&Klds[st * 16 + l16][quad * 8]);
            bf16x8 kb1 = ld16(&Klds[st * 16 + l16][32 + quad * 8]);
            z4 = __builtin_amdgcn_mfma_f32_16x16x32_bf16(kb0, qf[0], z4, 0, 0, 0);
            z4 = __builtin_amdgcn_mfma_f32_16x16x32_bf16(kb1, qf[1], z4, 0, 0, 0);
            s_acc[st] = z4;   // s_acc[st][r] = S^T[key=st*16+quad*4+r][q=l16]
        }

        if (lastchunk && it == iters - 1) {
            const int key0 = kbeg + it * 128 + quad * 4;
            const int qg = qt * 64 + wave * 16 + l16;
#pragma unroll
            for (int st = 0; st < 8; st++)
#pragma unroll
                for (int r = 0; r < 4; r++)
                    if (key0 + st * 16 + r > qg)
                        s_acc[st][r] = -1e30f;
        }

        // per-lane column softmax (q = wave*16 + l16)
        float lmax = s_acc[0][0];
#pragma unroll
        for (int st = 0; st < 8; st++)
#pragma unroll
            for (int r = 0; r < 4; r++) lmax = fmaxf(lmax, s_acc[st][r]);
        lmax = fmaxf(lmax, __shfl_xor(lmax, 16, 64));
        lmax = fmaxf(lmax, __shfl_xor(lmax, 32, 64));

        const float mnew = fmaxf(mrow, lmax);
        const float alpha = __expf(mrow - mnew);
        mrow = mnew;

        float p[8][4];
        float psum = 0.f;
#pragma unroll
        for (int st = 0; st < 8; st++)
#pragma unroll
            for (int r = 0; r < 4; r++) {
                p[st][r] = __expf(s_acc[st][r] - mnew);
                psum += p[st][r];
            }
        psum += __shfl_xor(psum, 16, 64);
        psum += __shfl_xor(psum, 32, 64);
        lrow = lrow * alpha + psum;

#pragma unroll
        for (int stf = 0; stf < 4; stf++)
#pragma unroll
            for (int r = 0; r < 4; r++) o_acc[stf][r] *= alpha;

        // P -> LDS, packed b64 (bank-clean): Plds[wave][l16][st*16+quad*4..+3]
#pragma unroll
        for (int st = 0; st < 8; st++) {
            uint2 u;
            u.x = pack2(p[st][0], p[st][1]);
            u.y = pack2(p[st][2], p[st][3]);
            st8(&Plds[wave][l16][st * 16 + quad * 4], u);
        }

        __syncthreads();   // order P round-trip (also keeps waves in step)

        // O^T += V^T P^T
        bf16x8 pt[4];
#pragma unroll
        for (int cc = 0; cc < 4; cc++)
            pt[cc] = ld16(&Plds[wave][l16][cc * 32 + quad * 8]);
#pragma unroll
        for (int stf = 0; stf < 4; stf++) {
#pragma unroll
            for (int cc = 0; cc < 4; cc++) {
                bf16x8 vb = ld16(&Vlds[stf * 16 + l16][cc * 32 + quad * 8]);
                o_acc[stf] = __builtin_amdgcn_mfma_f32_16x16x32_bf16(
                    vb, pt[cc], o_acc[stf], 0, 0, 0);
            }
        }
    }

    // write unnormalized partials (bf16), O^T -> [q][feat] packed stores
    unsigned short* Op = Opart + (size_t)ci * 4096;
    const int q = wave * 16 + l16;
#pragma unroll
    for (int stf = 0; stf < 4; stf++) {
        uint2 u;
        u.x = pack2(o_acc[stf][0], o_acc[stf][1]);
        u.y = pack2(o_acc[stf][2], o_acc[stf][3]);
        st8(&Op[q * 64 + stf * 16 + quad * 4], u);
    }
    if (quad == 0) {
        ml[(size_t)ci * 128 + q]      = mrow;
        ml[(size_t)ci * 128 + 64 + q] = lrow;
    }
}

// ---------------------------------------------------------------------------
// Combine: merge <=4 bf16 partials per (bh, qt) into Z [B,S,H*M] bf16.
// ---------------------------------------------------------------------------
__global__ void combine(const unsigned short* __restrict__ Opart,
                        const float* __restrict__ ml,
                        unsigned short* __restrict__ Z)
{
    const int qt = blockIdx.x, bh = blockIdx.y;
    const int b = bh / H_, h = bh - b * H_;
    const int g = qt >> 3, r7 = qt & 7;
    const int nc = g + 1;
    const int base = bh * NCHUNK_ + qt + 4 * g * (g - 1) + r7 * g;

    const int t = threadIdx.x;
    const int q = t >> 2, fs = (t & 3) * 16;

    float m_c[4], l_c[4];
    float M = NEG_BIG;
    for (int c = 0; c < nc; c++) {
        m_c[c] = ml[(size_t)(base + c) * 128 + q];
        l_c[c] = ml[(size_t)(base + c) * 128 + 64 + q];
        M = fmaxf(M, m_c[c]);
    }
    float L = 0.f;
    float w_c[4];
    for (int c = 0; c < nc; c++) {
        w_c[c] = __expf(m_c[c] - M);
        L += l_c[c] * w_c[c];
    }
    const float invL = 1.0f / L;

    float o[16] = {};
    for (int c = 0; c < nc; c++) {
        const unsigned short* op =
            Opart + (size_t)(base + c) * 4096 + q * 64 + fs;
        const float wc = w_c[c];
        float f[8];
        b82f(ld16u(op), f);
#pragma unroll
        for (int j = 0; j < 8; j++) o[j] += wc * f[j];
        b82f(ld16u(op + 8), f);
#pragma unroll
        for (int j = 0; j < 8; j++) o[8 + j] += wc * f[j];
    }

    unsigned short* zp =
        Z + ((size_t)b * S_ + qt * 64 + q) * (H_ * M_) + h * M_ + fs;
    uint4 u0, u1;
    u0.x = pack2(o[0]*invL,  o[1]*invL);  u0.y = pack2(o[2]*invL,  o[3]*invL);
    u0.z = pack2(o[4]*invL,  o[5]*invL);  u0.w = pack2(o[6]*invL,  o[7]*invL);
    u1.x = pack2(o[8]*invL,  o[9]*invL);  u1.y = pack2(o[10]*invL, o[11]*invL);
    u1.z = pack2(o[12]*invL, o[13]*invL); u1.w = pack2(o[14]*invL, o[15]*invL);
    st16(zp, u0);
    st16(zp + 8, u1);
}

// ---------------------------------------------------------------------------
// Output projection GEMM (async LDS staging).  grid (32,6).
// ---------------------------------------------------------------------------
__global__ __launch_bounds__(256, 2) void oproj_gemm(
    const unsigned short* __restrict__ Zin,   // [4096][768] bf16
    const unsigned short* __restrict__ WOT,   // [768][768] bf16 (B^T)
    const float* __restrict__ bO,             // [768] fp32
    float* __restrict__ out)                  // [4096][768] fp32
{
    const int row0 = blockIdx.x * 128;
    const int col0 = blockIdx.y * 128;
    const int t = threadIdx.x;
    const int w = t >> 6, lane = t & 63, quad = lane >> 4, l16 = lane & 15;
    const int wrow0 = (w & 1) * 64, wcol0 = (w >> 1) * 64;

    __shared__ unsigned short Alds[128 * 64];
    __shared__ unsigned short Blds[128 * 64];

    f32x4 acc[4][4] = {};

    const unsigned short* asrc[4];
    const unsigned short* bsrc[4];
    int ldsoff[4];
#pragma unroll
    for (int q = 0; q < 4; q++) {
        const int cq = w * 256 + q * 64 + lane;
        const int row = cq >> 3, c = cq & 7;
        const int cs = c ^ (row & 7);
        asrc[q] = Zin + (size_t)(row0 + row) * D_ + cs * 8;
        bsrc[q] = WOT + (size_t)(col0 + row) * D_ + cs * 8;
        ldsoff[q] = (w * 256 + q * 64) * 8;
    }
    const int swz = (l16 & 7);

    for (int k0 = 0; k0 < D_; k0 += 64) {
#pragma unroll
        for (int q = 0; q < 4; q++) async16(asrc[q] + k0, Alds + ldsoff[q]);
#pragma unroll
        for (int q = 0; q < 4; q++) async16(bsrc[q] + k0, Blds + ldsoff[q]);
        __syncthreads();

        bf16x8 af[4][2], bfm[4][2];
#pragma unroll
        for (int rt = 0; rt < 4; rt++) {
            const int row = wrow0 + rt * 16 + l16;
#pragma unroll
            for (int hh = 0; hh < 2; hh++)
                af[rt][hh] = ld16(&Alds[row * 64 + ((hh * 4 + quad) ^ swz) * 8]);
        }
#pragma unroll
        for (int st = 0; st < 4; st++) {
            const int row = wcol0 + st * 16 + l16;
#pragma unroll
            for (int hh = 0; hh < 2; hh++)
                bfm[st][hh] = ld16(&Blds[row * 64 + ((hh * 4 + quad) ^ swz) * 8]);
        }
#pragma unroll
        for (int rt = 0; rt < 4; rt++)
#pragma unroll
            for (int st = 0; st < 4; st++) {
                acc[rt][st] = __builtin_amdgcn_mfma_f32_16x16x32_bf16(
                    af[rt][0], bfm[st][0], acc[rt][st], 0, 0, 0);
                acc[rt][st] = __builtin_amdgcn_mfma_f32_16x16x32_bf16(
                    af[rt][1], bfm[st][1], acc[rt][st], 0, 0, 0);
            }
        __syncthreads();
    }

#pragma unroll
    for (int st = 0; st < 4; st++) {
        const int c = col0 + wcol0 + st * 16 + l16;
        const float bval = bO[c];
#pragma unroll
        for (int rt = 0; rt < 4; rt++)
#pragma unroll
            for (int rr = 0; rr < 4; rr++) {
                const int R = row0 + wrow0 + rt * 16 + quad * 4 + rr;
                out[(size_t)R * D_ + c] = acc[rt][st][rr] + bval;
            }
    }
}

// ---------------------------------------------------------------------------
extern "C" void kernel_launch(void* const* d_in, const int* in_sizes, int n_in,
                              void* d_out, int out_size, void* d_ws, size_t ws_size,
                              hipStream_t stream)
{
    const float* x  = (const float*)d_in[0];
    const float* WQ = (const float*)d_in[1];
    const float* bQ = (const float*)d_in[2];
    const float* WK = (const float*)d_in[3];
    const float* bK = (const float*)d_in[4];
    const float* WV = (const float*)d_in[5];
    const float* bV = (const float*)d_in[6];
    const float* WO = (const float*)d_in[7];
    const float* bO = (const float*)d_in[8];
    float* out = (float*)d_out;

    const size_t n = (size_t)B_ * H_ * S_ * M_;     // 3,145,728 elems
    unsigned short* q_ws  = (unsigned short*)d_ws;  // [B,H,S,M] bf16 (scaled)
    unsigned short* k_ws  = q_ws + n;               // [B,H,S,M]
    unsigned short* vt_ws = k_ws + n;               // [B,H,M,S] (transposed!)
    unsigned short* z_ws  = vt_ws + n;              // [B,S,H*M]
    unsigned short* WT    = z_ws + n;               // [2304][768]
    unsigned short* WOT   = WT + (size_t)NQKV_ * D_;// [768][768]
    unsigned short* xb    = WOT + (size_t)D_ * D_;  // [4096][768]
    unsigned short* Opart = xb + (size_t)BS_ * D_;  // [1920][4096] bf16
    float* mlbuf = (float*)(Opart + (size_t)TOTCHUNK_ * 4096); // [1920][128]

    prep<<<dim3(1056), 256, 0, stream>>>(WQ, WK, WV, WO, x, WT, WOT, xb);
    qkv_gemm<<<dim3(BS_ / 128, NQKV_ / 128), 256, 0, stream>>>(
        xb, WT, bQ, bK, bV, q_ws, k_ws, vt_ws);
    attn_split<<<dim3(NCHUNK_, B_ * H_), 256, 0, stream>>>(
        q_ws, k_ws, vt_ws, Opart, mlbuf);
    combine<<<dim3(S_ / 64, B_ * H_), 256, 0, stream>>>(Opart, mlbuf, z_ws);
    oproj_gemm<<<dim3(BS_ / 128, D_ / 128), 256, 0, stream>>>(
        z_ws, WOT, bO, out);
}